// Round 3
// baseline (245.304 us; speedup 1.0000x reference)
//
#include <hip/hip_runtime.h>
#include <hip/hip_bf16.h>
#include <stdint.h>

// ---- types ----
typedef float   floatx4  __attribute__((ext_vector_type(4)));
typedef float   floatx16 __attribute__((ext_vector_type(16)));
typedef int     intx4    __attribute__((ext_vector_type(4)));
typedef int     intx8    __attribute__((ext_vector_type(8)));
typedef _Float16 halfx8  __attribute__((ext_vector_type(8)));
typedef _Float16 halfx4  __attribute__((ext_vector_type(4)));
typedef _Float16 half2v  __attribute__((ext_vector_type(2)));
typedef short   short2v  __attribute__((ext_vector_type(2)));
typedef unsigned short ushort8 __attribute__((ext_vector_type(8)));

#define NROW 8192
#define NDIM 2048        // elements = bytes (fp8)
#define BM 128
#define SLICE 64         // bytes per row per K-slice = K=64 fp8 (one 32x32x64 MFMA)
#define NSLICE 32        // NDIM / SLICE
#define NSTRIP 64                       // NROW/BM
#define NOFF (NSTRIP*(NSTRIP-1)/2)      // 2016 off-diagonal tiles (dispatched first)
#define NTILE (NSTRIP*(NSTRIP+1)/2)     // 2080 total tiles
#define DT_LD 136        // Dt row stride in halves (272 B; rows 16B-aligned)
#define KL_SYM 64        // one 5-list per row per other-strip
#define SLOT_P 8         // halves per list slot: 5 values + 3 sentinel pads (16B)
#define MERGE_BLOCKS 256 // k_merge_sym grid

// insert v into descending-sorted a[5] (keeps 5 largest)  [f32 scalar]
__device__ __forceinline__ void ins_desc(float (&a)[5], float v) {
#pragma unroll
    for (int k = 0; k < 5; ++k) { float hi = fmaxf(a[k], v); float lo = fminf(a[k], v); a[k] = hi; v = lo; }
}
// insert v into ascending-sorted a[5] (keeps 5 smallest)  [f32 scalar]
__device__ __forceinline__ void ins_asc(float (&a)[5], float v) {
#pragma unroll
    for (int k = 0; k < 5; ++k) { float lo = fminf(a[k], v); float hi = fmaxf(a[k], v); a[k] = lo; v = hi; }
}

// ---- packed-f16 helpers (R12): v_pk_* process 2 columns per instruction ----
__device__ __forceinline__ int   h2bits(half2v v) { return __builtin_bit_cast(int, v); }
__device__ __forceinline__ half2v bits2h(int v)   { return __builtin_bit_cast(half2v, v); }
// (m & a) | (~m & b) -> v_bfi_b32
__device__ __forceinline__ int bfi(int m, int a, int b) { return (m & a) | (~m & b); }
// per-16-bit-half: 0xFFFF if half != 0 (general; halves may exceed 0x7FFF)
__device__ __forceinline__ int nzmask16(int v) {
    short2v s = __builtin_bit_cast(short2v, v);
    short2v n = (short2v)(0) - s;                 // v_pk_sub_i16
    int o = v | __builtin_bit_cast(int, n);       // sign set iff half != 0
    short2v m = __builtin_bit_cast(short2v, o) >> 15;  // v_pk_ashrrev_i16
    return __builtin_bit_cast(int, m);
}
// per-16-bit-half: 0xFFFF if half != 0; requires halves < 0x8000 (true for cam nibble)
__device__ __forceinline__ int nzmask16_small(int v) {
    short2v s = __builtin_bit_cast(short2v, v);
    short2v n = (short2v)(0) - s;                 // v_pk_sub_i16 (sign set iff 0<half<0x8000)
    short2v m = n >> 15;                          // v_pk_ashrrev_i16
    return __builtin_bit_cast(int, m);
}
// packed insertion: two independent desc-sorted top-5 lists (lo/hi half)
__device__ __forceinline__ void ins_desc2(half2v (&a)[5], half2v v) {
#pragma unroll
    for (int k = 0; k < 5; ++k) {
        half2v hi = __builtin_elementwise_max(a[k], v);
        half2v lo = __builtin_elementwise_min(a[k], v);
        a[k] = hi; v = lo;
    }
}
__device__ __forceinline__ void ins_asc2(half2v (&a)[5], half2v v) {
#pragma unroll
    for (int k = 0; k < 5; ++k) {
        half2v lo = __builtin_elementwise_min(a[k], v);
        half2v hi = __builtin_elementwise_max(a[k], v);
        a[k] = lo; v = hi;
    }
}

__device__ __forceinline__ void load_lds16(const void* g, void* l) {
    // async global->LDS, 16B/lane, dest = wave-uniform base + lane*16
    __builtin_amdgcn_global_load_lds((__attribute__((address_space(1))) void*)(void*)g,
                                     (__attribute__((address_space(3))) void*)l,
                                     16, 0, 0);
}

// ---- kernel 1: L2 normalize rows, write fp8-e4m3 matrix + sq ----
__global__ __launch_bounds__(256) void k_normalize(const float* __restrict__ feats,
                                                   unsigned char* __restrict__ xb,
                                                   float* __restrict__ sq) {
    const int lane = threadIdx.x & 63;
    const int row = (blockIdx.x << 2) + (threadIdx.x >> 6);
    const float* f = feats + (size_t)row * NDIM;
    float4 v[8];
    float ss = 0.f;
#pragma unroll
    for (int i = 0; i < 8; ++i) {
        v[i] = *(const float4*)(f + ((i << 6) + lane) * 4);
        ss += v[i].x * v[i].x + v[i].y * v[i].y + v[i].z * v[i].z + v[i].w * v[i].w;
    }
#pragma unroll
    for (int o = 32; o > 0; o >>= 1) ss += __shfl_xor(ss, o);
    float inv = 1.0f / fmaxf(sqrtf(ss), 1e-12f);
    if (lane == 0) sq[row] = ss * inv * inv;
    unsigned char* xo = xb + (size_t)row * NDIM;
#pragma unroll
    for (int i = 0; i < 8; ++i) {
        int w0 = __builtin_amdgcn_cvt_pk_fp8_f32(v[i].x * inv, v[i].y * inv, 0, false);
        w0     = __builtin_amdgcn_cvt_pk_fp8_f32(v[i].z * inv, v[i].w * inv, w0, true);
        *(int*)(xo + ((i << 6) + lane) * 4) = w0;
    }
}

// ---- scan helper (R12: packed-f16, 2 cols/instruction; additive chunk rotate) ----
__device__ __forceinline__ void scan_half_row(const _Float16* Dt_,
        const unsigned short* labcam_cols,
        int srow, int shalf, int pli, float (&pos5)[5], float (&neg5)[5]) {
    const int jb = shalf * 64;
    const int s2 = 2 * (srow & 7);
    const int pli2 = pli * 0x00010001;
    const int ONE2  = 0x3C003C00;   // half2(1.0, 1.0)
    const int BOOST2= 0x398E398E;   // half2(1/1.44) = 0.694336
    const int PINF2 = 0x7C007C00;
    const int NINF2 = 0xFC00FC00;
    half2v p5[5], n5[5];
#pragma unroll
    for (int k = 0; k < 5; ++k) { p5[k] = bits2h(NINF2); n5[k] = bits2h(PINF2); }
#pragma unroll
    for (int c8 = 0; c8 < 8; ++c8) {
        const int pc = ((shalf * 8 + c8) + s2) & 15;      // physical 16B chunk
        intx4 v  = *(const intx4*)(Dt_ + srow * DT_LD + pc * 8);
        intx4 lc = *(const intx4*)(labcam_cols + jb + c8 * 8);
#pragma unroll
        for (int e = 0; e < 4; ++e) {
            const int d2p = v[e];                 // 2 packed f16 d2 values
            const int x   = pli2 ^ lc[e];         // 2 packed (label<<4|cam) xors
            const int mdl = nzmask16(x & 0xFFF0FFF0);       // FFFF = diff label
            const int mdc = nzmask16_small(x & 0x000F000F); // FFFF = diff cam
            // negative: diff label; same-cam boost d2 * (1/1.44) (monotone in dist/1.2)
            const int mul = bfi(mdc, ONE2, BOOST2);
            half2v nv = bits2h(d2p) * bits2h(mul);          // v_pk_mul_f16
            nv = bits2h(bfi(mdl, h2bits(nv), PINF2));       // same-label -> +inf
            ins_asc2(n5, nv);                               // unconditional: P(any-lane insert)~1
            // positive: same label AND diff cam (i==j auto-excluded: same cam)
            const int pmask = mdc & ~mdl;
            half2v pv = bits2h(bfi(pmask, d2p, NINF2));
            half2v chk = __builtin_elementwise_max(pv, p5[4]);
            if (h2bits(chk) != h2bits(p5[4])) ins_desc2(p5, pv);  // ~40% taken
        }
    }
    // fold hi-halves into lo halves: rotate 16 and insert (top5 ⊆ union of half-top5s)
    half2v tp[5], tn[5];
#pragma unroll
    for (int k = 0; k < 5; ++k) {
        tp[k] = bits2h((int)__builtin_amdgcn_alignbit((unsigned)h2bits(p5[k]), (unsigned)h2bits(p5[k]), 16));
        tn[k] = bits2h((int)__builtin_amdgcn_alignbit((unsigned)h2bits(n5[k]), (unsigned)h2bits(n5[k]), 16));
    }
#pragma unroll
    for (int k = 0; k < 5; ++k) { ins_desc2(p5, tp[k]); ins_asc2(n5, tn[k]); }
#pragma unroll
    for (int k = 0; k < 5; ++k) { pos5[k] = (float)p5[k][0]; neg5[k] = (float)n5[k][0]; }
}

// merge the two half-row lists (adjacent lanes; snapshot-then-insert) and emit.
// [slot][row] layout, 16B slots -> ONE coalesced b128 store per list.
__device__ __forceinline__ void emit_lists(float (&pos5)[5], float (&neg5)[5], int shalf,
        _Float16* posp, _Float16* negp, int gi, int slot) {
    float tp[5], tn[5];
#pragma unroll
    for (int k = 0; k < 5; ++k) { tp[k] = __shfl_xor(pos5[k], 1); tn[k] = __shfl_xor(neg5[k], 1); }
#pragma unroll
    for (int k = 0; k < 5; ++k) {
        if (tp[k] > pos5[4]) ins_desc(pos5, tp[k]);
        if (tn[k] < neg5[4]) ins_asc(neg5, tn[k]);
    }
    if (shalf == 0) {
        const float NINF = -__builtin_inff(), PINF = __builtin_inff();
        halfx8 hp, hn;
#pragma unroll
        for (int k = 0; k < 5; ++k) { hp[k] = (_Float16)pos5[k]; hn[k] = (_Float16)neg5[k]; }
        hp[5] = hp[6] = hp[7] = (_Float16)NINF;
        hn[5] = hn[6] = hn[7] = (_Float16)PINF;
        const size_t off = ((size_t)slot * NROW + gi) * SLOT_P;
        *(halfx8*)(posp + off) = hp;
        *(halfx8*)(negp + off) = hn;
    }
}

// ---- kernel 2 (sym): R14 = 32x32x64 MFMA (K=64 slices) + slice-granular
// double-buffer.  Staging dbuf shrinks 64KB -> 32KB (2 bufs x (A 8KB + B 8KB)),
// Dt (34.8KB) aliases it -> 36.8KB total -> 3 blocks/CU (R13's 64KB dbuf
// capped at 2; no pipe >46% = latency-bound, so occupancy is the lever).
// Same LDS-read volume & read:MFMA cycle ratio (~1.4) as R13.
// A operand: lane l = row (l&31), k-bytes 32*(l>>5) (blocked-K, same family as
// the verified 16x16x128: row l&15, bytes 32*(l>>4)).
// C layout 32x32: col = lane&31, row = (reg&3)+8*(reg>>2)+4*(lane>>5).
// 64B-row bank swizzle: additive key (row>>1)&3 over 4 chunks -> 2-phase floor.
// + XCD-chunked tile decode (NOFF = 2016 = 8*252 exactly, bijective).
__global__ __launch_bounds__(256, 3) void k_gemm_sym(
        const unsigned char* __restrict__ xb, const float* __restrict__ sq,
        const int* __restrict__ labels, const int* __restrict__ camids,
        _Float16* __restrict__ posp, _Float16* __restrict__ negp) {
    __shared__ __align__(16) char smem[36864];
    // staging buf b: As_b = smem + b*16384 (8KB), Bs_b = As_b + 8192 (8KB)
    _Float16* Dt = (_Float16*)smem;           // [0, 34816) aliases staging
    float* sqr_s = (float*)(smem + 34816);    // 512 B
    float* sqc_s = sqr_s + BM;                // 512 B
    unsigned short* labcam_a = (unsigned short*)(sqc_s + BM);  // 256 B
    unsigned short* labcam_b = labcam_a + BM;                  // 256 B

    const int tid = threadIdx.x;
    const int w = tid >> 6, lane = tid & 63;
    const int wm = w >> 1, wn = w & 1;

    // tile decode: XCD-chunked over off-diagonal pairs (b<a); diagonals last
    int a, b;
    {
        int bx = blockIdx.x;
        int orig;
        if (bx < NOFF) orig = (bx & 7) * (NOFF / 8) + (bx >> 3);  // XCD x -> contiguous range
        else orig = bx;
        if (orig < NOFF) {
            a = (int)((1.0f + sqrtf(8.0f * (float)orig + 1.0f)) * 0.5f);
            while (a * (a - 1) / 2 > orig) --a;
            while (a * (a + 1) / 2 <= orig) ++a;
            b = orig - a * (a - 1) / 2;
        } else {
            a = b = orig - NOFF;
        }
    }
    const int r0 = a * BM, c0 = b * BM;

    // staging: 64 lanes x 16B = 16 rows x 64B per issue.
    // LDS[row][p] = G[row][(p - key)&3], key = (row>>1)&3  (additive rotate)
    const int lr = lane >> 2;                          // row within 16-row chunk
    const int lc = (((lane & 3) - ((lane >> 3) & 3)) & 3) * 16;  // src chunk bytes

    auto stage = [&](int buf, int koff) {
        char* Asb = smem + (buf << 14);
        char* Bsb = Asb + 8192;
#pragma unroll
        for (int q = 0; q < 2; ++q) {
            const int ra = w * 32 + q * 16;            // wave-uniform 16-row chunk
            load_lds16(xb + (size_t)(r0 + ra + lr) * NDIM + koff + lc, Asb + ra * SLICE);
            load_lds16(xb + (size_t)(c0 + ra + lr) * NDIM + koff + lc, Bsb + ra * SLICE);
        }
    };

    stage(0, 0);                     // prefetch first K-slice before anything else

    if (tid < BM) {
        int gi = r0 + tid;
        sqr_s[tid] = sq[gi];
        labcam_a[tid] = (unsigned short)((labels[gi] << 4) | camids[gi]);
    } else {
        int t2 = tid - BM;
        int gj = c0 + t2;
        sqc_s[t2] = sq[gj];
        labcam_b[t2] = (unsigned short)((labels[gj] << 4) | camids[gj]);
    }

    const int srow = tid >> 1;       // scan: 2 threads per row
    const int shalf = tid & 1;

    const int m32 = lane & 31;                 // operand row/col within 32-tile
    const int hi = lane >> 5;                  // k-half selector
    const int key = (lane >> 1) & 3;           // = ((lane&31)>>1)&3, frag-read swizzle
    const int p0 = ((2 * hi + key) & 3) * 16;  // physical byte offset of logical chunk 2*hi
    const int p1 = ((2 * hi + 1 + key) & 3) * 16;

    floatx16 acc[2][2];
#pragma unroll
    for (int ti = 0; ti < 2; ++ti)
#pragma unroll
        for (int tj = 0; tj < 2; ++tj)
#pragma unroll
            for (int r = 0; r < 16; ++r) acc[ti][tj][r] = 0.f;

    __syncthreads();                 // slice0 landed (vmcnt0) + side arrays visible

    for (int s = 0; s < NSLICE; ++s) {   // 2-phase: prefetch s+1 || compute s
        const int cur = s & 1;
        if (s < NSLICE - 1) stage(cur ^ 1, (s + 1) * SLICE);
        const char* Ab = smem + (cur << 14);
        const char* Bb = Ab + 8192;
        intx8 bf[2];
#pragma unroll
        for (int tj = 0; tj < 2; ++tj) {
            const char* bp = Bb + (wn * 64 + tj * 32 + m32) * SLICE;
            intx4 lo = *(const intx4*)(bp + p0);
            intx4 hi4 = *(const intx4*)(bp + p1);
            bf[tj] = __builtin_shufflevector(lo, hi4, 0, 1, 2, 3, 4, 5, 6, 7);
        }
        __builtin_amdgcn_s_setprio(1);
#pragma unroll
        for (int ti = 0; ti < 2; ++ti) {
            const char* ap = Ab + (wm * 64 + ti * 32 + m32) * SLICE;
            intx4 lo = *(const intx4*)(ap + p0);
            intx4 hi4 = *(const intx4*)(ap + p1);
            intx8 af = __builtin_shufflevector(lo, hi4, 0, 1, 2, 3, 4, 5, 6, 7);
            acc[ti][0] = __builtin_amdgcn_mfma_scale_f32_32x32x64_f8f6f4(
                af, bf[0], acc[ti][0], 0, 0, 0, 127, 0, 127);
            acc[ti][1] = __builtin_amdgcn_mfma_scale_f32_32x32x64_f8f6f4(
                af, bf[1], acc[ti][1], 0, 0, 0, 127, 0, 127);
        }
        __builtin_amdgcn_s_setprio(0);
        __syncthreads();             // retires buf reads; drains prefetch (issued before compute)
    }
    // last iter's syncthreads retired all staging reads -> Dt overwrite safe

    // ---- pass 1: d2 row-major (additive chunk rotate); scan rows of strip a ----
    // 32x32 C layout: col = lane&31, row = (reg&3)+8*(reg>>2)+4*hi
#pragma unroll
    for (int ti = 0; ti < 2; ++ti) {
#pragma unroll
        for (int tj = 0; tj < 2; ++tj) {
            const int jl = wn * 64 + tj * 32 + m32;
            const float sj = sqc_s[jl];
#pragma unroll
            for (int r = 0; r < 16; ++r) {
                const int il = wm * 64 + ti * 32 + (r & 3) + 8 * (r >> 2) + 4 * hi;
                float d2 = fmaxf(sqr_s[il] + sj - 2.0f * acc[ti][tj][r], 1e-12f);
                const int pch = (((jl >> 3) + 2 * (il & 7)) & 15);
                Dt[il * DT_LD + (pch << 3) + (jl & 7)] = (_Float16)d2;
            }
        }
    }
    __syncthreads();

    float pos5[5], neg5[5];
    scan_half_row(Dt, labcam_b, srow, shalf, (int)labcam_a[srow], pos5, neg5);
    emit_lists(pos5, neg5, shalf, posp, negp, r0 + srow, b);

    if (a != b) {
        __syncthreads();             // pass-1 scan reads done before Dt overwrite
        // ---- pass 2: d2 transposed (halfx4 packed, additive rotate); scan rows of strip b ----
#pragma unroll
        for (int tj = 0; tj < 2; ++tj) {
#pragma unroll
            for (int ti = 0; ti < 2; ++ti) {
                const int jl = wn * 64 + tj * 32 + m32;   // now the Dt row
                const float sj = sqc_s[jl];
                const int cw2 = 2 * (jl & 7);
#pragma unroll
                for (int rq = 0; rq < 4; ++rq) {          // reg quad -> 4 consecutive rows
                    const int base_row = wm * 64 + ti * 32 + 8 * rq + 4 * hi;
                    halfx4 h;
#pragma unroll
                    for (int e = 0; e < 4; ++e) {
                        const int il = base_row + e;
                        h[e] = (_Float16)fmaxf(sqr_s[il] + sj - 2.0f * acc[ti][tj][rq * 4 + e], 1e-12f);
                    }
                    const int pch = (((base_row >> 3) + cw2) & 15);
                    *(halfx4*)(Dt + jl * DT_LD + (pch << 3) + 4 * hi) = h;
                }
            }
        }
        __syncthreads();
        scan_half_row(Dt, labcam_a, srow, shalf, (int)labcam_b[srow], pos5, neg5);
        emit_lists(pos5, neg5, shalf, posp, negp, c0 + srow, a);
    }
}

// ---- kernel 3: merge 64 fp16 d2-lists/row.  [slot][row] layout -> coalesced.
__global__ __launch_bounds__(256) void k_merge_sym(const _Float16* __restrict__ posp,
        const _Float16* __restrict__ negp, const int* __restrict__ epoch_p,
        float* __restrict__ out, float* __restrict__ wsum_p, float* __restrict__ wpsum_p) {
    const int t = threadIdx.x;
    const int rl = t & 31;                      // row within block
    const int sg = t >> 5;                      // slot group 0..7 (8 slots each)
    const int row = blockIdx.x * 32 + rl;
    const float NINF = -__builtin_inff(), PINF = __builtin_inff();
    float p5[5] = {NINF, NINF, NINF, NINF, NINF};
    float n5[5] = {PINF, PINF, PINF, PINF, PINF};
    const size_t rbase = (size_t)row * SLOT_P;
#pragma unroll
    for (int s = 0; s < 8; ++s) {
        const size_t off = (size_t)(sg * 8 + s) * ((size_t)NROW * SLOT_P) + rbase;
        halfx8 pv = *(const halfx8*)(posp + off);
        halfx8 nv = *(const halfx8*)(negp + off);
#pragma unroll
        for (int e = 0; e < 8; ++e) { float f = (float)pv[e]; if (f > p5[4]) ins_desc(p5, f); }
#pragma unroll
        for (int e = 0; e < 8; ++e) { float f = (float)nv[e]; if (f < n5[4]) ins_asc(n5, f); }
    }
    __shared__ __align__(16) _Float16 lp[32][8][8];
    __shared__ __align__(16) _Float16 ln[32][8][8];
    const int sw = (sg + rl) & 7;               // bank-spread the 16B stash slots
    {
        halfx8 hp, hn;
#pragma unroll
        for (int k = 0; k < 5; ++k) { hp[k] = (_Float16)p5[k]; hn[k] = (_Float16)n5[k]; }
        hp[5] = hp[6] = hp[7] = (_Float16)NINF;
        hn[5] = hn[6] = hn[7] = (_Float16)PINF;
        *(halfx8*)&lp[rl][sw][0] = hp;
        *(halfx8*)&ln[rl][sw][0] = hn;
    }
    __syncthreads();
    if (t < 32) {
        float P5[5] = {NINF, NINF, NINF, NINF, NINF};
        float N5[5] = {PINF, PINF, PINF, PINF, PINF};
#pragma unroll
        for (int g = 0; g < 8; ++g) {
            halfx8 pv = *(const halfx8*)&lp[t][g][0];
            halfx8 nv = *(const halfx8*)&ln[t][g][0];
#pragma unroll
            for (int e = 0; e < 8; ++e) { float f = (float)pv[e]; if (f > P5[4]) ins_desc(P5, f); }
#pragma unroll
            for (int e = 0; e < 8; ++e) { float f = (float)nv[e]; if (f < N5[4]) ins_asc(N5, f); }
        }
        // d2 -> dist on the 5 survivors only
        float s = 0.f; int c = 0;
#pragma unroll
        for (int k = 0; k < 5; ++k) { bool fin = (P5[k] > NINF); s += fin ? sqrtf(P5[k]) : 0.f; c += fin ? 1 : 0; }
        float d_ap = (c > 0) ? s / (float)c : NINF;
        s = 0.f; c = 0;
#pragma unroll
        for (int k = 0; k < 5; ++k) { bool fin = (N5[k] < PINF); s += fin ? sqrtf(N5[k]) : 0.f; c += fin ? 1 : 0; }
        float d_an = (c > 0) ? s / (float)c : PINF;

        const int orow = blockIdx.x * 32 + t;
        out[1 + orow] = d_ap;
        out[1 + NROW + orow] = d_an;
        float diff = d_ap - d_an;
        float w0 = 1.0f / (1.0f + expf(-2.0f * diff));       // sigmoid(ALPHA*(d_ap-d_an))
        float p;
        if (*epoch_p < 10) {
            p = fmaxf(diff, 0.0f) + log1pf(expf(-fabsf(diff)));  // stable softplus
        } else {
            p = fmaxf(diff + 0.3f, 0.0f);                    // relu(d_ap - d_an + MARGIN)
        }
        float wp = w0 * p;
#pragma unroll
        for (int o = 16; o > 0; o >>= 1) { w0 += __shfl_down(w0, o, 32); wp += __shfl_down(wp, o, 32); }
        if (t == 0) { wsum_p[blockIdx.x] = w0; wpsum_p[blockIdx.x] = wp; }
    }
}

// ---- kernel 4: finalize loss scalar (256 partials, one wave) ----
__global__ void k_finalize(const float* __restrict__ wsum_p, const float* __restrict__ wpsum_p,
                           float* __restrict__ out) {
    const int t = threadIdx.x;   // 64 threads
    float sw  = wsum_p[t] + wsum_p[t + 64] + wsum_p[t + 128] + wsum_p[t + 192];
    float swp = wpsum_p[t] + wpsum_p[t + 64] + wpsum_p[t + 128] + wpsum_p[t + 192];
#pragma unroll
    for (int o = 32; o > 0; o >>= 1) { sw += __shfl_down(sw, o); swp += __shfl_down(swp, o); }
    if (t == 0) {
        float M = fmaxf(sw / (float)NROW, 1e-12f);
        out[0] = swp / ((float)NROW * M);
    }
}

extern "C" void kernel_launch(void* const* d_in, const int* in_sizes, int n_in,
                              void* d_out, int out_size, void* d_ws, size_t ws_size,
                              hipStream_t stream) {
    const float* feats  = (const float*)d_in[0];
    const int*   labels = (const int*)d_in[1];
    const int*   camids = (const int*)d_in[2];
    const int*   epoch  = (const int*)d_in[3];
    float* out = (float*)d_out;
    char* ws = (char*)d_ws;

    // workspace layout (~33.6 MB; ws proven >= 44 MB in R4-R11)
    unsigned char* xb = (unsigned char*)ws;                            // 16,777,216 B
    float* sq = (float*)(ws + 16777216);                               //     32,768 B
    const size_t LIST_HALVES = (size_t)KL_SYM * NROW * SLOT_P;         // 4,194,304 halves = 8 MB
    _Float16* posp = (_Float16*)(ws + 16777216 + 32768);
    _Float16* negp = posp + LIST_HALVES;
    float* wsum_p  = (float*)((char*)(posp + 2 * LIST_HALVES));
    float* wpsum_p = wsum_p + MERGE_BLOCKS;

    k_normalize<<<NROW / 4, 256, 0, stream>>>(feats, xb, sq);
    k_gemm_sym<<<NTILE, 256, 0, stream>>>(xb, sq, labels, camids, posp, negp);
    k_merge_sym<<<MERGE_BLOCKS, 256, 0, stream>>>(posp, negp, epoch, out, wsum_p, wpsum_p);
    k_finalize<<<1, 64, 0, stream>>>(wsum_p, wpsum_p, out);
}

// Round 4
// 236.519 us; speedup vs baseline: 1.0371x; 1.0371x over previous
//
#include <hip/hip_runtime.h>
#include <hip/hip_bf16.h>
#include <stdint.h>

// ---- types ----
typedef float   floatx4  __attribute__((ext_vector_type(4)));
typedef float   floatx16 __attribute__((ext_vector_type(16)));
typedef int     intx4    __attribute__((ext_vector_type(4)));
typedef int     intx8    __attribute__((ext_vector_type(8)));
typedef _Float16 halfx8  __attribute__((ext_vector_type(8)));
typedef _Float16 halfx4  __attribute__((ext_vector_type(4)));
typedef _Float16 half2v  __attribute__((ext_vector_type(2)));
typedef short   short2v  __attribute__((ext_vector_type(2)));
typedef unsigned short ushort8 __attribute__((ext_vector_type(8)));

#define NROW 8192
#define NDIM 2048        // elements = bytes (fp8)
#define BM 128
#define SLICE 64         // bytes per row per K-slice = K=64 fp8 (one 32x32x64 MFMA)
#define NSLICE 32        // NDIM / SLICE
#define NSTRIP 64                       // NROW/BM
#define NOFF (NSTRIP*(NSTRIP-1)/2)      // 2016 off-diagonal tiles (dispatched first)
#define NTILE (NSTRIP*(NSTRIP+1)/2)     // 2080 total tiles
#define DT_LD 136        // Dt row stride in halves (272 B; rows 16B-aligned)
#define KL_SYM 64        // one 5-list per row per other-strip
#define SLOT_P 8         // halves per list slot: 5 values + 3 sentinel pads (16B)
#define MERGE_BLOCKS 256 // k_merge_sym grid

// insert v into descending-sorted a[5] (keeps 5 largest)  [f32 scalar]
__device__ __forceinline__ void ins_desc(float (&a)[5], float v) {
#pragma unroll
    for (int k = 0; k < 5; ++k) { float hi = fmaxf(a[k], v); float lo = fminf(a[k], v); a[k] = hi; v = lo; }
}
// insert v into ascending-sorted a[5] (keeps 5 smallest)  [f32 scalar]
__device__ __forceinline__ void ins_asc(float (&a)[5], float v) {
#pragma unroll
    for (int k = 0; k < 5; ++k) { float lo = fminf(a[k], v); float hi = fmaxf(a[k], v); a[k] = lo; v = hi; }
}

// ---- packed-f16 helpers (R12): v_pk_* process 2 columns per instruction ----
__device__ __forceinline__ int   h2bits(half2v v) { return __builtin_bit_cast(int, v); }
__device__ __forceinline__ half2v bits2h(int v)   { return __builtin_bit_cast(half2v, v); }
// (m & a) | (~m & b) -> v_bfi_b32
__device__ __forceinline__ int bfi(int m, int a, int b) { return (m & a) | (~m & b); }
// per-16-bit-half: 0xFFFF if half != 0 (general; halves may exceed 0x7FFF)
__device__ __forceinline__ int nzmask16(int v) {
    short2v s = __builtin_bit_cast(short2v, v);
    short2v n = (short2v)(0) - s;                 // v_pk_sub_i16
    int o = v | __builtin_bit_cast(int, n);       // sign set iff half != 0
    short2v m = __builtin_bit_cast(short2v, o) >> 15;  // v_pk_ashrrev_i16
    return __builtin_bit_cast(int, m);
}
// per-16-bit-half: 0xFFFF if half != 0; requires halves < 0x8000 (true for cam nibble)
__device__ __forceinline__ int nzmask16_small(int v) {
    short2v s = __builtin_bit_cast(short2v, v);
    short2v n = (short2v)(0) - s;                 // v_pk_sub_i16 (sign set iff 0<half<0x8000)
    short2v m = n >> 15;                          // v_pk_ashrrev_i16
    return __builtin_bit_cast(int, m);
}
// packed insertion: two independent desc-sorted top-5 lists (lo/hi half)
__device__ __forceinline__ void ins_desc2(half2v (&a)[5], half2v v) {
#pragma unroll
    for (int k = 0; k < 5; ++k) {
        half2v hi = __builtin_elementwise_max(a[k], v);
        half2v lo = __builtin_elementwise_min(a[k], v);
        a[k] = hi; v = lo;
    }
}
__device__ __forceinline__ void ins_asc2(half2v (&a)[5], half2v v) {
#pragma unroll
    for (int k = 0; k < 5; ++k) {
        half2v lo = __builtin_elementwise_min(a[k], v);
        half2v hi = __builtin_elementwise_max(a[k], v);
        a[k] = lo; v = hi;
    }
}

__device__ __forceinline__ void load_lds16(const void* g, void* l) {
    // async global->LDS, 16B/lane, dest = wave-uniform base + lane*16
    __builtin_amdgcn_global_load_lds((__attribute__((address_space(1))) void*)(void*)g,
                                     (__attribute__((address_space(3))) void*)l,
                                     16, 0, 0);
}

// ---- kernel 1: L2 normalize rows, write fp8-e4m3 matrix + sq ----
__global__ __launch_bounds__(256) void k_normalize(const float* __restrict__ feats,
                                                   unsigned char* __restrict__ xb,
                                                   float* __restrict__ sq) {
    const int lane = threadIdx.x & 63;
    const int row = (blockIdx.x << 2) + (threadIdx.x >> 6);
    const float* f = feats + (size_t)row * NDIM;
    float4 v[8];
    float ss = 0.f;
#pragma unroll
    for (int i = 0; i < 8; ++i) {
        v[i] = *(const float4*)(f + ((i << 6) + lane) * 4);
        ss += v[i].x * v[i].x + v[i].y * v[i].y + v[i].z * v[i].z + v[i].w * v[i].w;
    }
#pragma unroll
    for (int o = 32; o > 0; o >>= 1) ss += __shfl_xor(ss, o);
    float inv = 1.0f / fmaxf(sqrtf(ss), 1e-12f);
    if (lane == 0) sq[row] = ss * inv * inv;
    unsigned char* xo = xb + (size_t)row * NDIM;
#pragma unroll
    for (int i = 0; i < 8; ++i) {
        int w0 = __builtin_amdgcn_cvt_pk_fp8_f32(v[i].x * inv, v[i].y * inv, 0, false);
        w0     = __builtin_amdgcn_cvt_pk_fp8_f32(v[i].z * inv, v[i].w * inv, w0, true);
        *(int*)(xo + ((i << 6) + lane) * 4) = w0;
    }
}

// ---- scan helper (R12: packed-f16, 2 cols/instruction; additive chunk rotate) ----
__device__ __forceinline__ void scan_half_row(const _Float16* Dt_,
        const unsigned short* labcam_cols,
        int srow, int shalf, int pli, float (&pos5)[5], float (&neg5)[5]) {
    const int jb = shalf * 64;
    const int s2 = 2 * (srow & 7);
    const int pli2 = pli * 0x00010001;
    const int ONE2  = 0x3C003C00;   // half2(1.0, 1.0)
    const int BOOST2= 0x398E398E;   // half2(1/1.44) = 0.694336
    const int PINF2 = 0x7C007C00;
    const int NINF2 = 0xFC00FC00;
    half2v p5[5], n5[5];
#pragma unroll
    for (int k = 0; k < 5; ++k) { p5[k] = bits2h(NINF2); n5[k] = bits2h(PINF2); }
#pragma unroll
    for (int c8 = 0; c8 < 8; ++c8) {
        const int pc = ((shalf * 8 + c8) + s2) & 15;      // physical 16B chunk
        intx4 v  = *(const intx4*)(Dt_ + srow * DT_LD + pc * 8);
        intx4 lc = *(const intx4*)(labcam_cols + jb + c8 * 8);
#pragma unroll
        for (int e = 0; e < 4; ++e) {
            const int d2p = v[e];                 // 2 packed f16 d2 values
            const int x   = pli2 ^ lc[e];         // 2 packed (label<<4|cam) xors
            const int mdl = nzmask16(x & 0xFFF0FFF0);       // FFFF = diff label
            const int mdc = nzmask16_small(x & 0x000F000F); // FFFF = diff cam
            // negative: diff label; same-cam boost d2 * (1/1.44) (monotone in dist/1.2)
            const int mul = bfi(mdc, ONE2, BOOST2);
            half2v nv = bits2h(d2p) * bits2h(mul);          // v_pk_mul_f16
            nv = bits2h(bfi(mdl, h2bits(nv), PINF2));       // same-label -> +inf
            ins_asc2(n5, nv);                               // unconditional: P(any-lane insert)~1
            // positive: same label AND diff cam (i==j auto-excluded: same cam)
            const int pmask = mdc & ~mdl;
            half2v pv = bits2h(bfi(pmask, d2p, NINF2));
            half2v chk = __builtin_elementwise_max(pv, p5[4]);
            if (h2bits(chk) != h2bits(p5[4])) ins_desc2(p5, pv);  // ~40% taken
        }
    }
    // fold hi-halves into lo halves: rotate 16 and insert (top5 ⊆ union of half-top5s)
    half2v tp[5], tn[5];
#pragma unroll
    for (int k = 0; k < 5; ++k) {
        tp[k] = bits2h((int)__builtin_amdgcn_alignbit((unsigned)h2bits(p5[k]), (unsigned)h2bits(p5[k]), 16));
        tn[k] = bits2h((int)__builtin_amdgcn_alignbit((unsigned)h2bits(n5[k]), (unsigned)h2bits(n5[k]), 16));
    }
#pragma unroll
    for (int k = 0; k < 5; ++k) { ins_desc2(p5, tp[k]); ins_asc2(n5, tn[k]); }
#pragma unroll
    for (int k = 0; k < 5; ++k) { pos5[k] = (float)p5[k][0]; neg5[k] = (float)n5[k][0]; }
}

// merge the two half-row lists (adjacent lanes; snapshot-then-insert) and emit.
// [slot][row] layout, 16B slots -> ONE coalesced b128 store per list.
__device__ __forceinline__ void emit_lists(float (&pos5)[5], float (&neg5)[5], int shalf,
        _Float16* posp, _Float16* negp, int gi, int slot) {
    float tp[5], tn[5];
#pragma unroll
    for (int k = 0; k < 5; ++k) { tp[k] = __shfl_xor(pos5[k], 1); tn[k] = __shfl_xor(neg5[k], 1); }
#pragma unroll
    for (int k = 0; k < 5; ++k) {
        if (tp[k] > pos5[4]) ins_desc(pos5, tp[k]);
        if (tn[k] < neg5[4]) ins_asc(neg5, tn[k]);
    }
    if (shalf == 0) {
        const float NINF = -__builtin_inff(), PINF = __builtin_inff();
        halfx8 hp, hn;
#pragma unroll
        for (int k = 0; k < 5; ++k) { hp[k] = (_Float16)pos5[k]; hn[k] = (_Float16)neg5[k]; }
        hp[5] = hp[6] = hp[7] = (_Float16)NINF;
        hn[5] = hn[6] = hn[7] = (_Float16)PINF;
        const size_t off = ((size_t)slot * NROW + gi) * SLOT_P;
        *(halfx8*)(posp + off) = hp;
        *(halfx8*)(negp + off) = hn;
    }
}

// ---- kernel 2 (sym): R15 = R14 geometry + T3/T4 counted-vmcnt pipeline.
// R14 post-mortem: __syncthreads' implicit s_waitcnt vmcnt(0) drained the
// prefetch issued in the SAME iteration -> every stage exposed
// max(0, load_latency - stage_compute), x32 stages.  Fix (T4, m218): 3 staging
// buffers, prefetch depth 2, raw s_barrier + counted s_waitcnt vmcnt(8)
// (retires only stage s; stages s+1/s+2 stay in flight ACROSS the barrier).
// vmcnt never reaches 0 in the main loop; each stage has 2 full iterations to
// land.  LDS 3x16KB staging (Dt aliases) + 2KB side = 51.2KB -> 3 blocks/CU.
__global__ __launch_bounds__(256, 3) void k_gemm_sym(
        const unsigned char* __restrict__ xb, const float* __restrict__ sq,
        const int* __restrict__ labels, const int* __restrict__ camids,
        _Float16* __restrict__ posp, _Float16* __restrict__ negp) {
    __shared__ __align__(16) char smem[49152 + 2048];
    // staging buf b at smem + b*16384: As 8KB + Bs 8KB
    _Float16* Dt = (_Float16*)smem;           // [0, 34816) aliases staging
    float* sqr_s = (float*)(smem + 49152);    // 512 B
    float* sqc_s = sqr_s + BM;                // 512 B
    unsigned short* labcam_a = (unsigned short*)(sqc_s + BM);  // 256 B
    unsigned short* labcam_b = labcam_a + BM;                  // 256 B

    const int tid = threadIdx.x;
    const int w = tid >> 6, lane = tid & 63;
    const int wm = w >> 1, wn = w & 1;

    // tile decode: XCD-chunked over off-diagonal pairs (b<a); diagonals last
    int a, b;
    {
        int bx = blockIdx.x;
        int orig;
        if (bx < NOFF) orig = (bx & 7) * (NOFF / 8) + (bx >> 3);  // XCD x -> contiguous range
        else orig = bx;
        if (orig < NOFF) {
            a = (int)((1.0f + sqrtf(8.0f * (float)orig + 1.0f)) * 0.5f);
            while (a * (a - 1) / 2 > orig) --a;
            while (a * (a + 1) / 2 <= orig) ++a;
            b = orig - a * (a - 1) / 2;
        } else {
            a = b = orig - NOFF;
        }
    }
    const int r0 = a * BM, c0 = b * BM;

    // staging: 64 lanes x 16B = 16 rows x 64B per issue.
    // LDS[row][p] = G[row][(p - key)&3], key = (row>>1)&3  (additive rotate)
    const int lr = lane >> 2;                          // row within 16-row chunk
    const int lc = (((lane & 3) - ((lane >> 3) & 3)) & 3) * 16;  // src chunk bytes

    auto stage = [&](int buf, int koff) {
        char* Asb = smem + (buf << 14);
        char* Bsb = Asb + 8192;
#pragma unroll
        for (int q = 0; q < 2; ++q) {
            const int ra = w * 32 + q * 16;            // wave-uniform 16-row chunk
            load_lds16(xb + (size_t)(r0 + ra + lr) * NDIM + koff + lc, Asb + ra * SLICE);
            load_lds16(xb + (size_t)(c0 + ra + lr) * NDIM + koff + lc, Bsb + ra * SLICE);
        }
    };

    // side arrays first (their vmcnt waits then don't drain the staging issues)
    if (tid < BM) {
        int gi = r0 + tid;
        sqr_s[tid] = sq[gi];
        labcam_a[tid] = (unsigned short)((labels[gi] << 4) | camids[gi]);
    } else {
        int t2 = tid - BM;
        int gj = c0 + t2;
        sqc_s[t2] = sq[gj];
        labcam_b[t2] = (unsigned short)((labels[gj] << 4) | camids[gj]);
    }

    stage(0, 0);                     // prefetch slices 0,1 (depth-2 pipeline fill)
    stage(1, SLICE);

    const int srow = tid >> 1;       // scan: 2 threads per row
    const int shalf = tid & 1;

    const int m32 = lane & 31;                 // operand row/col within 32-tile
    const int hi = lane >> 5;                  // k-half selector
    const int key = (lane >> 1) & 3;           // = ((lane&31)>>1)&3, frag-read swizzle
    const int p0 = ((2 * hi + key) & 3) * 16;  // physical byte offset of logical chunk 2*hi
    const int p1 = ((2 * hi + 1 + key) & 3) * 16;

    floatx16 acc[2][2];
#pragma unroll
    for (int ti = 0; ti < 2; ++ti)
#pragma unroll
        for (int tj = 0; tj < 2; ++tj)
#pragma unroll
            for (int r = 0; r < 16; ++r) acc[ti][tj][r] = 0.f;

    int bc = 0;                      // consume-buffer index (rotates 0,1,2)
    for (int s = 0; s < NSLICE; ++s) {
        if (s + 2 < NSLICE) {
            int bs = bc + 2; if (bs >= 3) bs -= 3;
            stage(bs, (s + 2) * SLICE);
        }
        // counted wait: retire ONLY stage s (oldest 4); keep s+1/s+2 in flight
        if (s < NSLICE - 2)       asm volatile("s_waitcnt vmcnt(8)" ::: "memory");
        else if (s == NSLICE - 2) asm volatile("s_waitcnt vmcnt(4)" ::: "memory");
        else                      asm volatile("s_waitcnt vmcnt(0)" ::: "memory");
        __builtin_amdgcn_s_barrier();            // all waves' stage-s writes landed
        asm volatile("" ::: "memory");

        const char* Ab = smem + (bc << 14);
        const char* Bb = Ab + 8192;
        intx8 bf[2];
#pragma unroll
        for (int tj = 0; tj < 2; ++tj) {
            const char* bp = Bb + (wn * 64 + tj * 32 + m32) * SLICE;
            intx4 lo = *(const intx4*)(bp + p0);
            intx4 hi4 = *(const intx4*)(bp + p1);
            bf[tj] = __builtin_shufflevector(lo, hi4, 0, 1, 2, 3, 4, 5, 6, 7);
        }
        __builtin_amdgcn_s_setprio(1);
#pragma unroll
        for (int ti = 0; ti < 2; ++ti) {
            const char* ap = Ab + (wm * 64 + ti * 32 + m32) * SLICE;
            intx4 lo = *(const intx4*)(ap + p0);
            intx4 hi4 = *(const intx4*)(ap + p1);
            intx8 af = __builtin_shufflevector(lo, hi4, 0, 1, 2, 3, 4, 5, 6, 7);
            acc[ti][0] = __builtin_amdgcn_mfma_scale_f32_32x32x64_f8f6f4(
                af, bf[0], acc[ti][0], 0, 0, 0, 127, 0, 127);
            acc[ti][1] = __builtin_amdgcn_mfma_scale_f32_32x32x64_f8f6f4(
                af, bf[1], acc[ti][1], 0, 0, 0, 127, 0, 127);
        }
        __builtin_amdgcn_s_setprio(0);
        // WAR guard: all waves' reads of buf bc done (retired via MFMA lgkm deps)
        // before iter s+1 stages into it.  No vmcnt drain here.
        asm volatile("" ::: "memory");
        __builtin_amdgcn_s_barrier();
        asm volatile("" ::: "memory");
        bc = (bc + 1 == 3) ? 0 : bc + 1;
    }
    // last iter: vmcnt(0) + both barriers -> staging fully quiesced; Dt safe

    // ---- pass 1: d2 row-major (additive chunk rotate); scan rows of strip a ----
    // 32x32 C layout: col = lane&31, row = (reg&3)+8*(reg>>2)+4*hi
#pragma unroll
    for (int ti = 0; ti < 2; ++ti) {
#pragma unroll
        for (int tj = 0; tj < 2; ++tj) {
            const int jl = wn * 64 + tj * 32 + m32;
            const float sj = sqc_s[jl];
#pragma unroll
            for (int r = 0; r < 16; ++r) {
                const int il = wm * 64 + ti * 32 + (r & 3) + 8 * (r >> 2) + 4 * hi;
                float d2 = fmaxf(sqr_s[il] + sj - 2.0f * acc[ti][tj][r], 1e-12f);
                const int pch = (((jl >> 3) + 2 * (il & 7)) & 15);
                Dt[il * DT_LD + (pch << 3) + (jl & 7)] = (_Float16)d2;
            }
        }
    }
    __syncthreads();

    float pos5[5], neg5[5];
    scan_half_row(Dt, labcam_b, srow, shalf, (int)labcam_a[srow], pos5, neg5);
    emit_lists(pos5, neg5, shalf, posp, negp, r0 + srow, b);

    if (a != b) {
        __syncthreads();             // pass-1 scan reads done before Dt overwrite
        // ---- pass 2: d2 transposed (halfx4 packed, additive rotate); scan rows of strip b ----
#pragma unroll
        for (int tj = 0; tj < 2; ++tj) {
#pragma unroll
            for (int ti = 0; ti < 2; ++ti) {
                const int jl = wn * 64 + tj * 32 + m32;   // now the Dt row
                const float sj = sqc_s[jl];
                const int cw2 = 2 * (jl & 7);
#pragma unroll
                for (int rq = 0; rq < 4; ++rq) {          // reg quad -> 4 consecutive rows
                    const int base_row = wm * 64 + ti * 32 + 8 * rq + 4 * hi;
                    halfx4 h;
#pragma unroll
                    for (int e = 0; e < 4; ++e) {
                        const int il = base_row + e;
                        h[e] = (_Float16)fmaxf(sqr_s[il] + sj - 2.0f * acc[ti][tj][rq * 4 + e], 1e-12f);
                    }
                    const int pch = (((base_row >> 3) + cw2) & 15);
                    *(halfx4*)(Dt + jl * DT_LD + (pch << 3) + 4 * hi) = h;
                }
            }
        }
        __syncthreads();
        scan_half_row(Dt, labcam_a, srow, shalf, (int)labcam_b[srow], pos5, neg5);
        emit_lists(pos5, neg5, shalf, posp, negp, c0 + srow, a);
    }
}

// ---- kernel 3: merge 64 fp16 d2-lists/row.  [slot][row] layout -> coalesced.
__global__ __launch_bounds__(256) void k_merge_sym(const _Float16* __restrict__ posp,
        const _Float16* __restrict__ negp, const int* __restrict__ epoch_p,
        float* __restrict__ out, float* __restrict__ wsum_p, float* __restrict__ wpsum_p) {
    const int t = threadIdx.x;
    const int rl = t & 31;                      // row within block
    const int sg = t >> 5;                      // slot group 0..7 (8 slots each)
    const int row = blockIdx.x * 32 + rl;
    const float NINF = -__builtin_inff(), PINF = __builtin_inff();
    float p5[5] = {NINF, NINF, NINF, NINF, NINF};
    float n5[5] = {PINF, PINF, PINF, PINF, PINF};
    const size_t rbase = (size_t)row * SLOT_P;
#pragma unroll
    for (int s = 0; s < 8; ++s) {
        const size_t off = (size_t)(sg * 8 + s) * ((size_t)NROW * SLOT_P) + rbase;
        halfx8 pv = *(const halfx8*)(posp + off);
        halfx8 nv = *(const halfx8*)(negp + off);
#pragma unroll
        for (int e = 0; e < 8; ++e) { float f = (float)pv[e]; if (f > p5[4]) ins_desc(p5, f); }
#pragma unroll
        for (int e = 0; e < 8; ++e) { float f = (float)nv[e]; if (f < n5[4]) ins_asc(n5, f); }
    }
    __shared__ __align__(16) _Float16 lp[32][8][8];
    __shared__ __align__(16) _Float16 ln[32][8][8];
    const int sw = (sg + rl) & 7;               // bank-spread the 16B stash slots
    {
        halfx8 hp, hn;
#pragma unroll
        for (int k = 0; k < 5; ++k) { hp[k] = (_Float16)p5[k]; hn[k] = (_Float16)n5[k]; }
        hp[5] = hp[6] = hp[7] = (_Float16)NINF;
        hn[5] = hn[6] = hn[7] = (_Float16)PINF;
        *(halfx8*)&lp[rl][sw][0] = hp;
        *(halfx8*)&ln[rl][sw][0] = hn;
    }
    __syncthreads();
    if (t < 32) {
        float P5[5] = {NINF, NINF, NINF, NINF, NINF};
        float N5[5] = {PINF, PINF, PINF, PINF, PINF};
#pragma unroll
        for (int g = 0; g < 8; ++g) {
            halfx8 pv = *(const halfx8*)&lp[t][g][0];
            halfx8 nv = *(const halfx8*)&ln[t][g][0];
#pragma unroll
            for (int e = 0; e < 8; ++e) { float f = (float)pv[e]; if (f > P5[4]) ins_desc(P5, f); }
#pragma unroll
            for (int e = 0; e < 8; ++e) { float f = (float)nv[e]; if (f < N5[4]) ins_asc(N5, f); }
        }
        // d2 -> dist on the 5 survivors only
        float s = 0.f; int c = 0;
#pragma unroll
        for (int k = 0; k < 5; ++k) { bool fin = (P5[k] > NINF); s += fin ? sqrtf(P5[k]) : 0.f; c += fin ? 1 : 0; }
        float d_ap = (c > 0) ? s / (float)c : NINF;
        s = 0.f; c = 0;
#pragma unroll
        for (int k = 0; k < 5; ++k) { bool fin = (N5[k] < PINF); s += fin ? sqrtf(N5[k]) : 0.f; c += fin ? 1 : 0; }
        float d_an = (c > 0) ? s / (float)c : PINF;

        const int orow = blockIdx.x * 32 + t;
        out[1 + orow] = d_ap;
        out[1 + NROW + orow] = d_an;
        float diff = d_ap - d_an;
        float w0 = 1.0f / (1.0f + expf(-2.0f * diff));       // sigmoid(ALPHA*(d_ap-d_an))
        float p;
        if (*epoch_p < 10) {
            p = fmaxf(diff, 0.0f) + log1pf(expf(-fabsf(diff)));  // stable softplus
        } else {
            p = fmaxf(diff + 0.3f, 0.0f);                    // relu(d_ap - d_an + MARGIN)
        }
        float wp = w0 * p;
#pragma unroll
        for (int o = 16; o > 0; o >>= 1) { w0 += __shfl_down(w0, o, 32); wp += __shfl_down(wp, o, 32); }
        if (t == 0) { wsum_p[blockIdx.x] = w0; wpsum_p[blockIdx.x] = wp; }
    }
}

// ---- kernel 4: finalize loss scalar (256 partials, one wave) ----
__global__ void k_finalize(const float* __restrict__ wsum_p, const float* __restrict__ wpsum_p,
                           float* __restrict__ out) {
    const int t = threadIdx.x;   // 64 threads
    float sw  = wsum_p[t] + wsum_p[t + 64] + wsum_p[t + 128] + wsum_p[t + 192];
    float swp = wpsum_p[t] + wpsum_p[t + 64] + wpsum_p[t + 128] + wpsum_p[t + 192];
#pragma unroll
    for (int o = 32; o > 0; o >>= 1) { sw += __shfl_down(sw, o); swp += __shfl_down(swp, o); }
    if (t == 0) {
        float M = fmaxf(sw / (float)NROW, 1e-12f);
        out[0] = swp / ((float)NROW * M);
    }
}

extern "C" void kernel_launch(void* const* d_in, const int* in_sizes, int n_in,
                              void* d_out, int out_size, void* d_ws, size_t ws_size,
                              hipStream_t stream) {
    const float* feats  = (const float*)d_in[0];
    const int*   labels = (const int*)d_in[1];
    const int*   camids = (const int*)d_in[2];
    const int*   epoch  = (const int*)d_in[3];
    float* out = (float*)d_out;
    char* ws = (char*)d_ws;

    // workspace layout (~33.6 MB; ws proven >= 44 MB in R4-R11)
    unsigned char* xb = (unsigned char*)ws;                            // 16,777,216 B
    float* sq = (float*)(ws + 16777216);                               //     32,768 B
    const size_t LIST_HALVES = (size_t)KL_SYM * NROW * SLOT_P;         // 4,194,304 halves = 8 MB
    _Float16* posp = (_Float16*)(ws + 16777216 + 32768);
    _Float16* negp = posp + LIST_HALVES;
    float* wsum_p  = (float*)((char*)(posp + 2 * LIST_HALVES));
    float* wpsum_p = wsum_p + MERGE_BLOCKS;

    k_normalize<<<NROW / 4, 256, 0, stream>>>(feats, xb, sq);
    k_gemm_sym<<<NTILE, 256, 0, stream>>>(xb, sq, labels, camids, posp, negp);
    k_merge_sym<<<MERGE_BLOCKS, 256, 0, stream>>>(posp, negp, epoch, out, wsum_p, wpsum_p);
    k_finalize<<<1, 64, 0, stream>>>(wsum_p, wpsum_p, out);
}

// Round 5
// 226.958 us; speedup vs baseline: 1.0808x; 1.0421x over previous
//
#include <hip/hip_runtime.h>
#include <hip/hip_bf16.h>
#include <stdint.h>

// ---- types ----
typedef float   floatx4  __attribute__((ext_vector_type(4)));
typedef float   floatx16 __attribute__((ext_vector_type(16)));
typedef int     intx4    __attribute__((ext_vector_type(4)));
typedef int     intx8    __attribute__((ext_vector_type(8)));
typedef _Float16 halfx8  __attribute__((ext_vector_type(8)));
typedef _Float16 halfx4  __attribute__((ext_vector_type(4)));
typedef _Float16 half2v  __attribute__((ext_vector_type(2)));

#define NROW 8192
#define NDIM 2048        // elements = bytes (fp8)
#define BM 128
#define SLICE 64         // bytes per row per K-slice = K=64 fp8 (one 32x32x64 MFMA)
#define NSLICE 32        // NDIM / SLICE
#define NSTRIP 64                       // NROW/BM
#define NOFF (NSTRIP*(NSTRIP-1)/2)      // 2016 off-diagonal tiles
#define NTILE (NSTRIP*(NSTRIP+1)/2)     // 2080 total tiles
#define DT_LD 136        // Dt row stride in halves (272 B; rows 16B-aligned)
#define KL_SYM 64        // one 5-list per row per other-strip
#define SLOT_P 8         // halves per list slot: 5 values + 3 sentinel pads (16B)
#define MERGE_BLOCKS 256 // k_merge_sym grid
#define BOOST_INV 0.6944444444f   // 1/1.44 (f32; closer to ref than old f16 0x398E)

// insert v into descending-sorted a[5] (keeps 5 largest)  [f32 scalar]
__device__ __forceinline__ void ins_desc(float (&a)[5], float v) {
#pragma unroll
    for (int k = 0; k < 5; ++k) { float hi = fmaxf(a[k], v); float lo = fminf(a[k], v); a[k] = hi; v = lo; }
}
// insert v into ascending-sorted a[5] (keeps 5 smallest)  [f32 scalar]
__device__ __forceinline__ void ins_asc(float (&a)[5], float v) {
#pragma unroll
    for (int k = 0; k < 5; ++k) { float lo = fminf(a[k], v); float hi = fmaxf(a[k], v); a[k] = lo; v = hi; }
}

__device__ __forceinline__ int   h2bits(half2v v) { return __builtin_bit_cast(int, v); }
__device__ __forceinline__ half2v bits2h(int v)   { return __builtin_bit_cast(half2v, v); }
// packed insertion: two independent sorted top-5 lists (lo/hi half)
__device__ __forceinline__ void ins_desc2(half2v (&a)[5], half2v v) {
#pragma unroll
    for (int k = 0; k < 5; ++k) {
        half2v hi = __builtin_elementwise_max(a[k], v);
        half2v lo = __builtin_elementwise_min(a[k], v);
        a[k] = hi; v = lo;
    }
}
__device__ __forceinline__ void ins_asc2(half2v (&a)[5], half2v v) {
#pragma unroll
    for (int k = 0; k < 5; ++k) {
        half2v lo = __builtin_elementwise_min(a[k], v);
        half2v hi = __builtin_elementwise_max(a[k], v);
        a[k] = lo; v = hi;
    }
}

__device__ __forceinline__ void load_lds16(const void* g, void* l) {
    // async global->LDS, 16B/lane, dest = wave-uniform base + lane*16
    __builtin_amdgcn_global_load_lds((__attribute__((address_space(1))) void*)(void*)g,
                                     (__attribute__((address_space(3))) void*)l,
                                     16, 0, 0);
}

// ---- kernel 1: L2 normalize rows, write fp8-e4m3 matrix + sq ----
__global__ __launch_bounds__(256) void k_normalize(const float* __restrict__ feats,
                                                   unsigned char* __restrict__ xb,
                                                   float* __restrict__ sq) {
    const int lane = threadIdx.x & 63;
    const int row = (blockIdx.x << 2) + (threadIdx.x >> 6);
    const float* f = feats + (size_t)row * NDIM;
    float4 v[8];
    float ss = 0.f;
#pragma unroll
    for (int i = 0; i < 8; ++i) {
        v[i] = *(const float4*)(f + ((i << 6) + lane) * 4);
        ss += v[i].x * v[i].x + v[i].y * v[i].y + v[i].z * v[i].z + v[i].w * v[i].w;
    }
#pragma unroll
    for (int o = 32; o > 0; o >>= 1) ss += __shfl_xor(ss, o);
    float inv = 1.0f / fmaxf(sqrtf(ss), 1e-12f);
    if (lane == 0) sq[row] = ss * inv * inv;
    unsigned char* xo = xb + (size_t)row * NDIM;
#pragma unroll
    for (int i = 0; i < 8; ++i) {
        int w0 = __builtin_amdgcn_cvt_pk_fp8_f32(v[i].x * inv, v[i].y * inv, 0, false);
        w0     = __builtin_amdgcn_cvt_pk_fp8_f32(v[i].z * inv, v[i].w * inv, w0, true);
        *(int*)(xo + ((i << 6) + lane) * 4) = w0;
    }
}

// ---- R16 scan: Dt holds PRE-CLASSIFIED nv (boosted d2; +inf for same-label/
// diag).  Classification is symmetric in (i,j) so the epilogue computes it once
// and BOTH passes scan insertion-only: load b128 + 4x ins_asc2.  (Was: 15 class
// ops + 10 neg + 7 pos per packed pair, twice.)
__device__ __forceinline__ void scan_half_row_neg(const _Float16* Dt_,
        int srow, int shalf, float (&neg5)[5]) {
    const int s2 = 2 * (srow & 7);
    const int PINF2 = 0x7C007C00;
    half2v n5[5];
#pragma unroll
    for (int k = 0; k < 5; ++k) n5[k] = bits2h(PINF2);
#pragma unroll
    for (int c8 = 0; c8 < 8; ++c8) {
        const int pc = ((shalf * 8 + c8) + s2) & 15;      // physical 16B chunk
        intx4 v = *(const intx4*)(Dt_ + srow * DT_LD + pc * 8);
#pragma unroll
        for (int e = 0; e < 4; ++e) ins_asc2(n5, bits2h(v[e]));
    }
    // fold hi-halves into lo halves (top5 ⊆ union of half-top5s)
    half2v tn[5];
#pragma unroll
    for (int k = 0; k < 5; ++k)
        tn[k] = bits2h((int)__builtin_amdgcn_alignbit((unsigned)h2bits(n5[k]), (unsigned)h2bits(n5[k]), 16));
#pragma unroll
    for (int k = 0; k < 5; ++k) ins_asc2(n5, tn[k]);
#pragma unroll
    for (int k = 0; k < 5; ++k) neg5[k] = (float)n5[k][0];
}

// merge the two half-row lists (adjacent lanes) and emit one coalesced b128
__device__ __forceinline__ void emit_neg(float (&neg5)[5], int shalf,
        _Float16* negp, int gi, int slot) {
    float tn[5];
#pragma unroll
    for (int k = 0; k < 5; ++k) tn[k] = __shfl_xor(neg5[k], 1);
#pragma unroll
    for (int k = 0; k < 5; ++k) { if (tn[k] < neg5[4]) ins_asc(neg5, tn[k]); }
    if (shalf == 0) {
        const float PINF = __builtin_inff();
        halfx8 hn;
#pragma unroll
        for (int k = 0; k < 5; ++k) hn[k] = (_Float16)neg5[k];
        hn[5] = hn[6] = hn[7] = (_Float16)PINF;
        *(halfx8*)(negp + ((size_t)slot * NROW + gi) * SLOT_P) = hn;
    }
}

// ---- kernel 2 (sym): R16 = R15 pipeline + symmetric-classified epilogue +
// neg-only scan.  Positives handled by k_pos (sparse: ~27/row, all within one
// label group).  acc is overwritten with nv in pass 1 so pass 2 re-layouts
// without recomputing d2/class.
__global__ __launch_bounds__(256, 3) void k_gemm_sym(
        const unsigned char* __restrict__ xb, const float* __restrict__ sq,
        const int* __restrict__ labels, const int* __restrict__ camids,
        _Float16* __restrict__ negp) {
    __shared__ __align__(16) char smem[49152 + 2048];
    _Float16* Dt = (_Float16*)smem;           // [0, 34816) aliases staging
    float* sqr_s = (float*)(smem + 49152);    // 512 B
    float* sqc_s = sqr_s + BM;                // 512 B
    unsigned short* labcam_a = (unsigned short*)(sqc_s + BM);  // 256 B
    unsigned short* labcam_b = labcam_a + BM;                  // 256 B

    const int tid = threadIdx.x;
    const int w = tid >> 6, lane = tid & 63;
    const int wm = w >> 1, wn = w & 1;

    // tile decode: XCD-chunked over off-diagonal pairs (b<a); diagonals last
    int a, b;
    {
        int bx = blockIdx.x;
        int orig;
        if (bx < NOFF) orig = (bx & 7) * (NOFF / 8) + (bx >> 3);
        else orig = bx;
        if (orig < NOFF) {
            a = (int)((1.0f + sqrtf(8.0f * (float)orig + 1.0f)) * 0.5f);
            while (a * (a - 1) / 2 > orig) --a;
            while (a * (a + 1) / 2 <= orig) ++a;
            b = orig - a * (a - 1) / 2;
        } else {
            a = b = orig - NOFF;
        }
    }
    const int r0 = a * BM, c0 = b * BM;

    // staging: 64 lanes x 16B = 16 rows x 64B per issue, additive chunk rotate
    const int lr = lane >> 2;
    const int lc = (((lane & 3) - ((lane >> 3) & 3)) & 3) * 16;

    auto stage = [&](int buf, int koff) {
        char* Asb = smem + (buf << 14);
        char* Bsb = Asb + 8192;
#pragma unroll
        for (int q = 0; q < 2; ++q) {
            const int ra = w * 32 + q * 16;
            load_lds16(xb + (size_t)(r0 + ra + lr) * NDIM + koff + lc, Asb + ra * SLICE);
            load_lds16(xb + (size_t)(c0 + ra + lr) * NDIM + koff + lc, Bsb + ra * SLICE);
        }
    };

    if (tid < BM) {
        int gi = r0 + tid;
        sqr_s[tid] = sq[gi];
        labcam_a[tid] = (unsigned short)((labels[gi] << 4) | camids[gi]);
    } else {
        int t2 = tid - BM;
        int gj = c0 + t2;
        sqc_s[t2] = sq[gj];
        labcam_b[t2] = (unsigned short)((labels[gj] << 4) | camids[gj]);
    }

    stage(0, 0);                     // depth-2 pipeline fill
    stage(1, SLICE);

    const int srow = tid >> 1;       // scan: 2 threads per row
    const int shalf = tid & 1;

    const int m32 = lane & 31;
    const int hi = lane >> 5;
    const int key = (lane >> 1) & 3;
    const int p0 = ((2 * hi + key) & 3) * 16;
    const int p1 = ((2 * hi + 1 + key) & 3) * 16;

    floatx16 acc[2][2];
#pragma unroll
    for (int ti = 0; ti < 2; ++ti)
#pragma unroll
        for (int tj = 0; tj < 2; ++tj)
#pragma unroll
            for (int r = 0; r < 16; ++r) acc[ti][tj][r] = 0.f;

    int bc = 0;
    for (int s = 0; s < NSLICE; ++s) {
        if (s + 2 < NSLICE) {
            int bs = bc + 2; if (bs >= 3) bs -= 3;
            stage(bs, (s + 2) * SLICE);
        }
        // counted wait (T4): retire ONLY stage s; keep s+1/s+2 in flight
        if (s < NSLICE - 2)       asm volatile("s_waitcnt vmcnt(8)" ::: "memory");
        else if (s == NSLICE - 2) asm volatile("s_waitcnt vmcnt(4)" ::: "memory");
        else                      asm volatile("s_waitcnt vmcnt(0)" ::: "memory");
        __builtin_amdgcn_s_barrier();
        asm volatile("" ::: "memory");

        const char* Ab = smem + (bc << 14);
        const char* Bb = Ab + 8192;
        intx8 bf[2];
#pragma unroll
        for (int tj = 0; tj < 2; ++tj) {
            const char* bp = Bb + (wn * 64 + tj * 32 + m32) * SLICE;
            intx4 lo = *(const intx4*)(bp + p0);
            intx4 hi4 = *(const intx4*)(bp + p1);
            bf[tj] = __builtin_shufflevector(lo, hi4, 0, 1, 2, 3, 4, 5, 6, 7);
        }
        __builtin_amdgcn_s_setprio(1);
#pragma unroll
        for (int ti = 0; ti < 2; ++ti) {
            const char* ap = Ab + (wm * 64 + ti * 32 + m32) * SLICE;
            intx4 lo = *(const intx4*)(ap + p0);
            intx4 hi4 = *(const intx4*)(ap + p1);
            intx8 af = __builtin_shufflevector(lo, hi4, 0, 1, 2, 3, 4, 5, 6, 7);
            acc[ti][0] = __builtin_amdgcn_mfma_scale_f32_32x32x64_f8f6f4(
                af, bf[0], acc[ti][0], 0, 0, 0, 127, 0, 127);
            acc[ti][1] = __builtin_amdgcn_mfma_scale_f32_32x32x64_f8f6f4(
                af, bf[1], acc[ti][1], 0, 0, 0, 127, 0, 127);
        }
        __builtin_amdgcn_s_setprio(0);
        asm volatile("" ::: "memory");
        __builtin_amdgcn_s_barrier();
        asm volatile("" ::: "memory");
        bc = (bc + 1 == 3) ? 0 : bc + 1;
    }

    // ---- pass 1: classify once (symmetric!), write nv row-major; acc := nv ----
    // 32x32 C layout: col = lane&31, row = (reg&3)+8*(reg>>2)+4*hi
    const float FINF = __builtin_inff();
#pragma unroll
    for (int ti = 0; ti < 2; ++ti) {
#pragma unroll
        for (int tj = 0; tj < 2; ++tj) {
            const int jl = wn * 64 + tj * 32 + m32;
            const float sj = sqc_s[jl];
            const int lb = (int)labcam_b[jl];
#pragma unroll
            for (int r = 0; r < 16; ++r) {
                const int il = wm * 64 + ti * 32 + (r & 3) + 8 * (r >> 2) + 4 * hi;
                float d2 = fmaxf(sqr_s[il] + sj - 2.0f * acc[ti][tj][r], 1e-12f);
                const int x = (int)labcam_a[il] ^ lb;
                float nv = (x & 15) ? d2 : d2 * BOOST_INV;   // same-cam neg boost
                nv = (x & 0xFFF0) ? nv : FINF;               // same-label (incl diag) -> +inf
                acc[ti][tj][r] = nv;                         // reuse in pass 2
                const int pch = ((jl >> 3) + 2 * (il & 7)) & 15;
                Dt[il * DT_LD + (pch << 3) + (jl & 7)] = (_Float16)nv;
            }
        }
    }
    __syncthreads();

    float neg5[5];
    scan_half_row_neg(Dt, srow, shalf, neg5);
    emit_neg(neg5, shalf, negp, r0 + srow, b);

    if (a != b) {
        __syncthreads();             // pass-1 scan reads done before Dt overwrite
        // ---- pass 2: re-layout nv transposed from acc (no recompute) ----
#pragma unroll
        for (int tj = 0; tj < 2; ++tj) {
#pragma unroll
            for (int ti = 0; ti < 2; ++ti) {
                const int jl = wn * 64 + tj * 32 + m32;   // Dt row
                const int cw2 = 2 * (jl & 7);
#pragma unroll
                for (int rq = 0; rq < 4; ++rq) {
                    const int base_row = wm * 64 + ti * 32 + 8 * rq + 4 * hi;
                    halfx4 h;
#pragma unroll
                    for (int e = 0; e < 4; ++e) h[e] = (_Float16)acc[ti][tj][rq * 4 + e];
                    const int pch = (((base_row >> 3) + cw2) & 15);
                    *(halfx4*)(Dt + jl * DT_LD + (pch << 3) + 4 * hi) = h;
                }
            }
        }
        __syncthreads();
        scan_half_row_neg(Dt, srow, shalf, neg5);
        emit_neg(neg5, shalf, negp, c0 + srow, a);
    }
}

// ---- kernel 2b: positives, sparse.  One block per label (256 blocks).
// All positives of a row lie in its label group (~32 rows).  Gather members,
// 64x64 Gram via the same 32x32x64 MX-fp8 MFMA path (sentinel-padded), per-row
// top-5 over cross-cam same-label pairs -> FINAL pos list posf[row][8].
__global__ __launch_bounds__(256) void k_pos(const unsigned char* __restrict__ xb,
        const float* __restrict__ sq, const int* __restrict__ labels,
        const int* __restrict__ camids, _Float16* __restrict__ posf) {
    __shared__ int mem[64];
    __shared__ unsigned short mlc[64];
    __shared__ float msq[64];
    __shared__ int cnt_s;
    __shared__ __align__(16) char stg[2][4096];     // [64 rows][64B] per buf
    __shared__ __align__(16) _Float16 D2[64][72];   // stride 144B (16B-aligned rows)

    const int t = threadIdx.x, L = blockIdx.x;
    if (t == 0) cnt_s = 0;
    __syncthreads();
    for (int i = t; i < NROW; i += 256) {
        if (labels[i] == L) {
            int slot = atomicAdd(&cnt_s, 1);
            if (slot < 64) mem[slot] = i;
        }
    }
    __syncthreads();
    const int cnt = min(cnt_s, 64);   // P(group>64) ~ 2e-6 for Bin(8192,1/256)
    if (t < 64) {
        if (t < cnt) {
            int gi = mem[t];
            mlc[t] = (unsigned short)((labels[gi] << 4) | camids[gi]);
            msq[t] = sq[gi];
        } else {
            mem[t] = 0; mlc[t] = 0xFFFF; msq[t] = 0.f;   // sentinel: never same-label
        }
    }
    __syncthreads();

    const int w = t >> 6, lane = t & 63;
    const int wm = w >> 1, wn = w & 1;
    const int lr = lane >> 2;
    const int lcb = (((lane & 3) - ((lane >> 3) & 3)) & 3) * 16;
    const int m32 = lane & 31, hi = lane >> 5;
    const int key = (lane >> 1) & 3;
    const int p0 = ((2 * hi + key) & 3) * 16;
    const int p1 = ((2 * hi + 1 + key) & 3) * 16;
    const int myrow = mem[w * 16 + lr];              // wave w stages rows w*16..+15

    auto pstage = [&](int buf, int koff) {
        load_lds16(xb + (size_t)myrow * NDIM + koff + lcb, &stg[buf][0] + w * 1024);
    };

    floatx16 acc;
#pragma unroll
    for (int r = 0; r < 16; ++r) acc[r] = 0.f;

    pstage(0, 0);
    __syncthreads();
    for (int s = 0; s < NSLICE; ++s) {
        if (s + 1 < NSLICE) pstage((s + 1) & 1, (s + 1) * SLICE);
        const char* Ab = &stg[s & 1][0];
        const char* ap = Ab + (wm * 32 + m32) * SLICE;
        intx4 alo = *(const intx4*)(ap + p0);
        intx4 ahi = *(const intx4*)(ap + p1);
        intx8 af = __builtin_shufflevector(alo, ahi, 0, 1, 2, 3, 4, 5, 6, 7);
        const char* bp = Ab + (wn * 32 + m32) * SLICE;
        intx4 blo = *(const intx4*)(bp + p0);
        intx4 bhi = *(const intx4*)(bp + p1);
        intx8 bf = __builtin_shufflevector(blo, bhi, 0, 1, 2, 3, 4, 5, 6, 7);
        acc = __builtin_amdgcn_mfma_scale_f32_32x32x64_f8f6f4(af, bf, acc, 0, 0, 0, 127, 0, 127);
        __syncthreads();
    }

    // epilogue: masked d2 -> D2[il][jl]; valid pos <=> same label (x&0xFFF0==0,
    // sentinels excluded) AND cross-cam (x&15 != 0; i==j auto-excluded)
    const float NINF = -__builtin_inff();
    {
        const int jl = wn * 32 + m32;
        const int lcj = (int)mlc[jl];
        const float sj = msq[jl];
#pragma unroll
        for (int r = 0; r < 16; ++r) {
            const int il = wm * 32 + (r & 3) + 8 * (r >> 2) + 4 * hi;
            float d2 = fmaxf(msq[il] + sj - 2.0f * acc[r], 1e-12f);
            const int x = (int)mlc[il] ^ lcj;
            bool posv = ((x & 0xFFF0) == 0) & ((x & 15) != 0);
            D2[il][jl] = posv ? (_Float16)d2 : (_Float16)NINF;
        }
    }
    __syncthreads();

    // per-row top5: 4 threads/row x 16 cols, packed insert + shfl merge
    {
        const int prow = t >> 2, q = t & 3;
        const int NINF2 = 0xFC00FC00;
        half2v p5h[5];
#pragma unroll
        for (int k = 0; k < 5; ++k) p5h[k] = bits2h(NINF2);
        const _Float16* dp = &D2[prow][q * 16];
        intx4 v0 = *(const intx4*)dp;
        intx4 v1 = *(const intx4*)(dp + 8);
#pragma unroll
        for (int e = 0; e < 4; ++e) ins_desc2(p5h, bits2h(v0[e]));
#pragma unroll
        for (int e = 0; e < 4; ++e) ins_desc2(p5h, bits2h(v1[e]));
        half2v tp[5];
#pragma unroll
        for (int k = 0; k < 5; ++k)
            tp[k] = bits2h((int)__builtin_amdgcn_alignbit((unsigned)h2bits(p5h[k]), (unsigned)h2bits(p5h[k]), 16));
#pragma unroll
        for (int k = 0; k < 5; ++k) ins_desc2(p5h, tp[k]);
        float p5[5];
#pragma unroll
        for (int k = 0; k < 5; ++k) p5[k] = (float)p5h[k][0];
#pragma unroll
        for (int o = 1; o <= 2; o <<= 1) {
            float tq[5];
#pragma unroll
            for (int k = 0; k < 5; ++k) tq[k] = __shfl_xor(p5[k], o);
#pragma unroll
            for (int k = 0; k < 5; ++k) { if (tq[k] > p5[4]) ins_desc(p5, tq[k]); }
        }
        if (q == 0 && prow < cnt) {
            halfx8 hp;
#pragma unroll
            for (int k = 0; k < 5; ++k) hp[k] = (_Float16)p5[k];
            hp[5] = hp[6] = hp[7] = (_Float16)NINF;
            *(halfx8*)(posf + (size_t)mem[prow] * SLOT_P) = hp;
        }
    }
}

// ---- kernel 3: merge 64 fp16 neg-lists/row + final pos list.  [slot][row]
// layout -> coalesced.  256 blocks x 256 thr (32 rows/block, 8 slot-groups).
__global__ __launch_bounds__(256) void k_merge_sym(const _Float16* __restrict__ negp,
        const _Float16* __restrict__ posf, const int* __restrict__ epoch_p,
        float* __restrict__ out, float* __restrict__ wsum_p, float* __restrict__ wpsum_p) {
    const int t = threadIdx.x;
    const int rl = t & 31;
    const int sg = t >> 5;
    const int row = blockIdx.x * 32 + rl;
    const float NINF = -__builtin_inff(), PINF = __builtin_inff();
    float n5[5] = {PINF, PINF, PINF, PINF, PINF};
    const size_t rbase = (size_t)row * SLOT_P;
#pragma unroll
    for (int s = 0; s < 8; ++s) {
        const size_t off = (size_t)(sg * 8 + s) * ((size_t)NROW * SLOT_P) + rbase;
        halfx8 nv = *(const halfx8*)(negp + off);
#pragma unroll
        for (int e = 0; e < 8; ++e) { float f = (float)nv[e]; if (f < n5[4]) ins_asc(n5, f); }
    }
    __shared__ __align__(16) _Float16 ln[32][8][8];
    const int sw = (sg + rl) & 7;
    {
        halfx8 hn;
#pragma unroll
        for (int k = 0; k < 5; ++k) hn[k] = (_Float16)n5[k];
        hn[5] = hn[6] = hn[7] = (_Float16)PINF;
        *(halfx8*)&ln[rl][sw][0] = hn;
    }
    __syncthreads();
    if (t < 32) {
        float N5[5] = {PINF, PINF, PINF, PINF, PINF};
#pragma unroll
        for (int g = 0; g < 8; ++g) {
            halfx8 nv = *(const halfx8*)&ln[t][g][0];
#pragma unroll
            for (int e = 0; e < 8; ++e) { float f = (float)nv[e]; if (f < N5[4]) ins_asc(N5, f); }
        }
        const int orow = blockIdx.x * 32 + t;
        halfx8 pv = *(const halfx8*)(posf + (size_t)orow * SLOT_P);
        // d2 -> dist on survivors only
        float s = 0.f; int c = 0;
#pragma unroll
        for (int k = 0; k < 5; ++k) { float f = (float)pv[k]; bool fin = (f > NINF); s += fin ? sqrtf(f) : 0.f; c += fin ? 1 : 0; }
        float d_ap = (c > 0) ? s / (float)c : NINF;
        s = 0.f; c = 0;
#pragma unroll
        for (int k = 0; k < 5; ++k) { bool fin = (N5[k] < PINF); s += fin ? sqrtf(N5[k]) : 0.f; c += fin ? 1 : 0; }
        float d_an = (c > 0) ? s / (float)c : PINF;

        out[1 + orow] = d_ap;
        out[1 + NROW + orow] = d_an;
        float diff = d_ap - d_an;
        float w0 = 1.0f / (1.0f + expf(-2.0f * diff));       // sigmoid(ALPHA*diff)
        float p;
        if (*epoch_p < 10) {
            p = fmaxf(diff, 0.0f) + log1pf(expf(-fabsf(diff)));  // stable softplus
        } else {
            p = fmaxf(diff + 0.3f, 0.0f);                    // relu(diff + MARGIN)
        }
        float wp = w0 * p;
#pragma unroll
        for (int o = 16; o > 0; o >>= 1) { w0 += __shfl_down(w0, o, 32); wp += __shfl_down(wp, o, 32); }
        if (t == 0) { wsum_p[blockIdx.x] = w0; wpsum_p[blockIdx.x] = wp; }
    }
}

// ---- kernel 4: finalize loss scalar (256 partials, one wave) ----
__global__ void k_finalize(const float* __restrict__ wsum_p, const float* __restrict__ wpsum_p,
                           float* __restrict__ out) {
    const int t = threadIdx.x;   // 64 threads
    float sw  = wsum_p[t] + wsum_p[t + 64] + wsum_p[t + 128] + wsum_p[t + 192];
    float swp = wpsum_p[t] + wpsum_p[t + 64] + wpsum_p[t + 128] + wpsum_p[t + 192];
#pragma unroll
    for (int o = 32; o > 0; o >>= 1) { sw += __shfl_down(sw, o); swp += __shfl_down(swp, o); }
    if (t == 0) {
        float M = fmaxf(sw / (float)NROW, 1e-12f);
        out[0] = swp / ((float)NROW * M);
    }
}

extern "C" void kernel_launch(void* const* d_in, const int* in_sizes, int n_in,
                              void* d_out, int out_size, void* d_ws, size_t ws_size,
                              hipStream_t stream) {
    const float* feats  = (const float*)d_in[0];
    const int*   labels = (const int*)d_in[1];
    const int*   camids = (const int*)d_in[2];
    const int*   epoch  = (const int*)d_in[3];
    float* out = (float*)d_out;
    char* ws = (char*)d_ws;

    // workspace layout (~24.4 MB; ws proven >= 44 MB in R4-R11)
    unsigned char* xb = (unsigned char*)ws;                            // 16,777,216 B
    float* sq = (float*)(ws + 16777216);                               //     32,768 B
    const size_t NEG_HALVES = (size_t)KL_SYM * NROW * SLOT_P;          // 8 MB
    _Float16* negp = (_Float16*)(ws + 16777216 + 32768);
    _Float16* posf = negp + NEG_HALVES;                                // 128 KB
    float* wsum_p  = (float*)((char*)(posf + (size_t)NROW * SLOT_P));
    float* wpsum_p = wsum_p + MERGE_BLOCKS;

    k_normalize<<<NROW / 4, 256, 0, stream>>>(feats, xb, sq);
    k_pos<<<256, 256, 0, stream>>>(xb, sq, labels, camids, posf);
    k_gemm_sym<<<NTILE, 256, 0, stream>>>(xb, sq, labels, camids, negp);
    k_merge_sym<<<MERGE_BLOCKS, 256, 0, stream>>>(negp, posf, epoch, out, wsum_p, wpsum_p);
    k_finalize<<<1, 64, 0, stream>>>(wsum_p, wpsum_p, out);
}

// Round 6
// 207.497 us; speedup vs baseline: 1.1822x; 1.0938x over previous
//
#include <hip/hip_runtime.h>
#include <hip/hip_bf16.h>
#include <stdint.h>

// ---- types ----
typedef float   floatx4  __attribute__((ext_vector_type(4)));
typedef float   floatx16 __attribute__((ext_vector_type(16)));
typedef int     intx4    __attribute__((ext_vector_type(4)));
typedef int     intx8    __attribute__((ext_vector_type(8)));
typedef _Float16 halfx8  __attribute__((ext_vector_type(8)));
typedef _Float16 halfx4  __attribute__((ext_vector_type(4)));
typedef _Float16 half2v  __attribute__((ext_vector_type(2)));

#define NROW 8192
#define NDIM 2048        // elements = bytes (fp8)
#define BM 128
#define SLICE 64         // bytes per row per K-slice = K=64 fp8 (one 32x32x64 MFMA)
#define NSLICE 32        // NDIM / SLICE
#define NSTRIP 64                       // NROW/BM
#define NTILE (NSTRIP*(NSTRIP+1)/2)     // 2080 total tiles (= 8*260 exactly)
#define NPOSB 256        // pos blocks prepended to the fused grid
#define DT_LD 136        // Dt row stride in halves (272 B; rows 16B-aligned)
#define KL_SYM 64        // one 5-list per row per other-strip
#define SLOT_P 8         // halves per list slot: 5 values + 3 sentinel pads (16B)
#define MERGE_BLOCKS 256 // k_merge_sym grid
#define BOOST_INV 0.6944444444f   // 1/1.44

// insert v into descending-sorted a[5] (keeps 5 largest)  [f32 scalar]
__device__ __forceinline__ void ins_desc(float (&a)[5], float v) {
#pragma unroll
    for (int k = 0; k < 5; ++k) { float hi = fmaxf(a[k], v); float lo = fminf(a[k], v); a[k] = hi; v = lo; }
}
// insert v into ascending-sorted a[5] (keeps 5 smallest)  [f32 scalar]
__device__ __forceinline__ void ins_asc(float (&a)[5], float v) {
#pragma unroll
    for (int k = 0; k < 5; ++k) { float lo = fminf(a[k], v); float hi = fmaxf(a[k], v); a[k] = lo; v = hi; }
}

__device__ __forceinline__ int   h2bits(half2v v) { return __builtin_bit_cast(int, v); }
__device__ __forceinline__ half2v bits2h(int v)   { return __builtin_bit_cast(half2v, v); }
// packed insertion: two independent sorted top-5 lists (lo/hi half)
__device__ __forceinline__ void ins_desc2(half2v (&a)[5], half2v v) {
#pragma unroll
    for (int k = 0; k < 5; ++k) {
        half2v hi = __builtin_elementwise_max(a[k], v);
        half2v lo = __builtin_elementwise_min(a[k], v);
        a[k] = hi; v = lo;
    }
}
__device__ __forceinline__ void ins_asc2(half2v (&a)[5], half2v v) {
#pragma unroll
    for (int k = 0; k < 5; ++k) {
        half2v lo = __builtin_elementwise_min(a[k], v);
        half2v hi = __builtin_elementwise_max(a[k], v);
        a[k] = lo; v = hi;
    }
}

__device__ __forceinline__ void load_lds16(const void* g, void* l) {
    // async global->LDS, 16B/lane, dest = wave-uniform base + lane*16
    __builtin_amdgcn_global_load_lds((__attribute__((address_space(1))) void*)(void*)g,
                                     (__attribute__((address_space(3))) void*)l,
                                     16, 0, 0);
}

// ---- kernel 1: L2 normalize rows, write fp8-e4m3 matrix + sq ----
__global__ __launch_bounds__(256) void k_normalize(const float* __restrict__ feats,
                                                   unsigned char* __restrict__ xb,
                                                   float* __restrict__ sq) {
    const int lane = threadIdx.x & 63;
    const int row = (blockIdx.x << 2) + (threadIdx.x >> 6);
    const float* f = feats + (size_t)row * NDIM;
    float4 v[8];
    float ss = 0.f;
#pragma unroll
    for (int i = 0; i < 8; ++i) {
        v[i] = *(const float4*)(f + ((i << 6) + lane) * 4);
        ss += v[i].x * v[i].x + v[i].y * v[i].y + v[i].z * v[i].z + v[i].w * v[i].w;
    }
#pragma unroll
    for (int o = 32; o > 0; o >>= 1) ss += __shfl_xor(ss, o);
    float inv = 1.0f / fmaxf(sqrtf(ss), 1e-12f);
    if (lane == 0) sq[row] = ss * inv * inv;
    unsigned char* xo = xb + (size_t)row * NDIM;
#pragma unroll
    for (int i = 0; i < 8; ++i) {
        int w0 = __builtin_amdgcn_cvt_pk_fp8_f32(v[i].x * inv, v[i].y * inv, 0, false);
        w0     = __builtin_amdgcn_cvt_pk_fp8_f32(v[i].z * inv, v[i].w * inv, w0, true);
        *(int*)(xo + ((i << 6) + lane) * 4) = w0;
    }
}

// ---- scan: Dt holds PRE-CLASSIFIED nv (boosted d2; +inf for same-label/diag).
// Insertion-only: load b128 + 4x ins_asc2.
__device__ __forceinline__ void scan_half_row_neg(const _Float16* Dt_,
        int srow, int shalf, float (&neg5)[5]) {
    const int s2 = 2 * (srow & 7);
    const int PINF2 = 0x7C007C00;
    half2v n5[5];
#pragma unroll
    for (int k = 0; k < 5; ++k) n5[k] = bits2h(PINF2);
#pragma unroll
    for (int c8 = 0; c8 < 8; ++c8) {
        const int pc = ((shalf * 8 + c8) + s2) & 15;      // physical 16B chunk
        intx4 v = *(const intx4*)(Dt_ + srow * DT_LD + pc * 8);
#pragma unroll
        for (int e = 0; e < 4; ++e) ins_asc2(n5, bits2h(v[e]));
    }
    // fold hi-halves into lo halves (top5 ⊆ union of half-top5s)
    half2v tn[5];
#pragma unroll
    for (int k = 0; k < 5; ++k)
        tn[k] = bits2h((int)__builtin_amdgcn_alignbit((unsigned)h2bits(n5[k]), (unsigned)h2bits(n5[k]), 16));
#pragma unroll
    for (int k = 0; k < 5; ++k) ins_asc2(n5, tn[k]);
#pragma unroll
    for (int k = 0; k < 5; ++k) neg5[k] = (float)n5[k][0];
}

// merge the two half-row lists (adjacent lanes) and emit one coalesced b128
__device__ __forceinline__ void emit_neg(float (&neg5)[5], int shalf,
        _Float16* negp, int gi, int slot) {
    float tn[5];
#pragma unroll
    for (int k = 0; k < 5; ++k) tn[k] = __shfl_xor(neg5[k], 1);
#pragma unroll
    for (int k = 0; k < 5; ++k) { if (tn[k] < neg5[4]) ins_asc(neg5, tn[k]); }
    if (shalf == 0) {
        const float PINF = __builtin_inff();
        halfx8 hn;
#pragma unroll
        for (int k = 0; k < 5; ++k) hn[k] = (_Float16)neg5[k];
        hn[5] = hn[6] = hn[7] = (_Float16)PINF;
        *(halfx8*)(negp + ((size_t)slot * NROW + gi) * SLOT_P) = hn;
    }
}

// ---- fused kernel 2: blocks [0,256) = positives path; [256, 256+2080) = tiles.
// R17: (a) k_pos fused in (hides its latency-bound runtime under the gemm span;
// R15-pattern 3-buf counted-vmcnt pipeline replaces drain-per-slice), (b) tile
// decode via 8x8-strip SUPERTILES (footprint 16 strips = 4MB = one XCD L2),
// XCD-chunked over 2080 = 8*260 exactly (bijective), (c) epilogue hoists
// col-side (2 values) and row-side LDS reads out of the inner loop.
__global__ __launch_bounds__(256, 3) void k_main(
        const unsigned char* __restrict__ xb, const float* __restrict__ sq,
        const int* __restrict__ labels, const int* __restrict__ camids,
        _Float16* __restrict__ negp, _Float16* __restrict__ posf) {
    __shared__ __align__(16) char smem[51200];

    const int tid = threadIdx.x;
    const int w = tid >> 6, lane = tid & 63;
    const int m32 = lane & 31;
    const int hi = lane >> 5;
    const int key = (lane >> 1) & 3;
    const int p0 = ((2 * hi + key) & 3) * 16;
    const int p1 = ((2 * hi + 1 + key) & 3) * 16;
    const float FINF = __builtin_inff();
    const float NINF = -FINF;

    if (blockIdx.x < NPOSB) {
        // ================= positives path (one block per label) =================
        char* stg0 = smem;                                   // 3 x 4096
        _Float16* D2 = (_Float16*)(smem + 12288);            // [64][72] halves
        int* mem = (int*)(smem + 21504);                     // 64 ints
        unsigned short* mlc = (unsigned short*)(smem + 21760);
        float* msq = (float*)(smem + 21888);
        int* cntp = (int*)(smem + 22144);

        const int L = blockIdx.x;
        if (tid == 0) *cntp = 0;
        __syncthreads();
        for (int i = tid; i < NROW; i += 256) {
            if (labels[i] == L) {
                int slot = atomicAdd(cntp, 1);
                if (slot < 64) mem[slot] = i;
            }
        }
        __syncthreads();
        const int cnt = min(*cntp, 64);   // P(group>64) ~ 2e-6
        if (tid < 64) {
            if (tid < cnt) {
                int gi = mem[tid];
                mlc[tid] = (unsigned short)((labels[gi] << 4) | camids[gi]);
                msq[tid] = sq[gi];
            } else {
                mem[tid] = 0; mlc[tid] = 0xFFFF; msq[tid] = 0.f;  // sentinel
            }
        }
        __syncthreads();

        const int wm = w >> 1, wn = w & 1;
        const int lr = lane >> 2;
        const int lcb = (((lane & 3) - ((lane >> 3) & 3)) & 3) * 16;
        const int myrow = mem[w * 16 + lr];          // wave w stages rows w*16..+15

        auto pstage = [&](int buf, int koff) {
            load_lds16(xb + (size_t)myrow * NDIM + koff + lcb,
                       stg0 + (buf << 12) + w * 1024);
        };

        floatx16 acc;
#pragma unroll
        for (int r = 0; r < 16; ++r) acc[r] = 0.f;

        pstage(0, 0);                    // depth-2 fill (1 load/wave/slice)
        pstage(1, SLICE);
        for (int s = 0; s < NSLICE; ++s) {
            if (s + 2 < NSLICE) {
                int bs = s + 2; bs -= (bs >= 3 ? 3 : 0); bs -= (bs >= 3 ? 3 : 0);
                pstage((s + 2) % 3, (s + 2) * SLICE);
            }
            if (s < NSLICE - 2)       asm volatile("s_waitcnt vmcnt(2)" ::: "memory");
            else if (s == NSLICE - 2) asm volatile("s_waitcnt vmcnt(1)" ::: "memory");
            else                      asm volatile("s_waitcnt vmcnt(0)" ::: "memory");
            __builtin_amdgcn_s_barrier();
            asm volatile("" ::: "memory");
            const char* Ab = stg0 + ((s % 3) << 12);
            const char* ap = Ab + (wm * 32 + m32) * SLICE;
            intx4 alo = *(const intx4*)(ap + p0);
            intx4 ahi = *(const intx4*)(ap + p1);
            intx8 af = __builtin_shufflevector(alo, ahi, 0, 1, 2, 3, 4, 5, 6, 7);
            const char* bp = Ab + (wn * 32 + m32) * SLICE;
            intx4 blo = *(const intx4*)(bp + p0);
            intx4 bhi = *(const intx4*)(bp + p1);
            intx8 bf = __builtin_shufflevector(blo, bhi, 0, 1, 2, 3, 4, 5, 6, 7);
            acc = __builtin_amdgcn_mfma_scale_f32_32x32x64_f8f6f4(af, bf, acc, 0, 0, 0, 127, 0, 127);
            asm volatile("" ::: "memory");
            __builtin_amdgcn_s_barrier();
            asm volatile("" ::: "memory");
        }

        // epilogue: masked d2 -> D2[il][jl]; valid pos <=> same label, cross-cam
        {
            const int jl = (w & 1) * 32 + m32;
            const int lcj = (int)mlc[jl];
            const float sj = msq[jl];
            const int wm2 = w >> 1;
#pragma unroll
            for (int r = 0; r < 16; ++r) {
                const int il = wm2 * 32 + (r & 3) + 8 * (r >> 2) + 4 * hi;
                float d2 = fmaxf(msq[il] + sj - 2.0f * acc[r], 1e-12f);
                const int x = (int)mlc[il] ^ lcj;
                bool posv = ((x & 0xFFF0) == 0) & ((x & 15) != 0);
                D2[il * 72 + jl] = posv ? (_Float16)d2 : (_Float16)NINF;
            }
        }
        __syncthreads();

        // per-row top5: 4 threads/row x 16 cols, packed insert + shfl merge
        {
            const int prow = tid >> 2, q = tid & 3;
            const int NINF2 = 0xFC00FC00;
            half2v p5h[5];
#pragma unroll
            for (int k = 0; k < 5; ++k) p5h[k] = bits2h(NINF2);
            const _Float16* dp = D2 + prow * 72 + q * 16;
            intx4 v0 = *(const intx4*)dp;
            intx4 v1 = *(const intx4*)(dp + 8);
#pragma unroll
            for (int e = 0; e < 4; ++e) ins_desc2(p5h, bits2h(v0[e]));
#pragma unroll
            for (int e = 0; e < 4; ++e) ins_desc2(p5h, bits2h(v1[e]));
            half2v tp[5];
#pragma unroll
            for (int k = 0; k < 5; ++k)
                tp[k] = bits2h((int)__builtin_amdgcn_alignbit((unsigned)h2bits(p5h[k]), (unsigned)h2bits(p5h[k]), 16));
#pragma unroll
            for (int k = 0; k < 5; ++k) ins_desc2(p5h, tp[k]);
            float p5[5];
#pragma unroll
            for (int k = 0; k < 5; ++k) p5[k] = (float)p5h[k][0];
#pragma unroll
            for (int o = 1; o <= 2; o <<= 1) {
                float tq[5];
#pragma unroll
                for (int k = 0; k < 5; ++k) tq[k] = __shfl_xor(p5[k], o);
#pragma unroll
                for (int k = 0; k < 5; ++k) { if (tq[k] > p5[4]) ins_desc(p5, tq[k]); }
            }
            if (q == 0 && prow < cnt) {
                halfx8 hp;
#pragma unroll
                for (int k = 0; k < 5; ++k) hp[k] = (_Float16)p5[k];
                hp[5] = hp[6] = hp[7] = (_Float16)NINF;
                *(halfx8*)(posf + (size_t)mem[prow] * SLOT_P) = hp;
            }
        }
        return;
    }

    // ================= tile (negatives) path =================
    _Float16* Dt = (_Float16*)smem;           // [0, 34816) aliases staging
    float* sqr_s = (float*)(smem + 49152);
    float* sqc_s = sqr_s + BM;
    unsigned short* labcam_a = (unsigned short*)(sqc_s + BM);
    unsigned short* labcam_b = labcam_a + BM;

    const int wm = w >> 1, wn = w & 1;

    // supertile decode; XCD-chunked (2080 = 8*260 exact, bijective)
    int a, b;
    {
        int bx = blockIdx.x - NPOSB;
        int o = (bx & 7) * (NTILE / 8) + (bx >> 3);
        if (o < 1792) {                          // 28 off-diag supertiles x 64
            int st = o >> 6;                     // SA>SB triangle, 8 strips
            int SA = (int)((1.0f + sqrtf(8.0f * (float)st + 1.0f)) * 0.5f);
            while (SA * (SA - 1) / 2 > st) --SA;
            while (SA * (SA + 1) / 2 <= st) ++SA;
            int SB = st - SA * (SA - 1) / 2;
            int inner = o & 63;
            a = SA * 8 + (inner >> 3);
            b = SB * 8 + (inner & 7);
        } else {                                 // 8 diag supertiles x 36
            int idx = o - 1792;
            int st = idx / 36;
            int inner = idx - st * 36;           // triangle incl diagonal
            int ia = (int)((sqrtf(8.0f * (float)inner + 1.0f) - 1.0f) * 0.5f);
            while (ia * (ia + 1) / 2 > inner) --ia;
            while ((ia + 1) * (ia + 2) / 2 <= inner) ++ia;
            int ib = inner - ia * (ia + 1) / 2;
            a = st * 8 + ia;
            b = st * 8 + ib;
        }
    }
    const int r0 = a * BM, c0 = b * BM;

    // staging: 64 lanes x 16B = 16 rows x 64B per issue, additive chunk rotate
    const int lr = lane >> 2;
    const int lc = (((lane & 3) - ((lane >> 3) & 3)) & 3) * 16;

    auto stage = [&](int buf, int koff) {
        char* Asb = smem + (buf << 14);
        char* Bsb = Asb + 8192;
#pragma unroll
        for (int q = 0; q < 2; ++q) {
            const int ra = w * 32 + q * 16;
            load_lds16(xb + (size_t)(r0 + ra + lr) * NDIM + koff + lc, Asb + ra * SLICE);
            load_lds16(xb + (size_t)(c0 + ra + lr) * NDIM + koff + lc, Bsb + ra * SLICE);
        }
    };

    if (tid < BM) {
        int gi = r0 + tid;
        sqr_s[tid] = sq[gi];
        labcam_a[tid] = (unsigned short)((labels[gi] << 4) | camids[gi]);
    } else {
        int t2 = tid - BM;
        int gj = c0 + t2;
        sqc_s[t2] = sq[gj];
        labcam_b[t2] = (unsigned short)((labels[gj] << 4) | camids[gj]);
    }

    stage(0, 0);                     // depth-2 pipeline fill
    stage(1, SLICE);

    const int srow = tid >> 1;       // scan: 2 threads per row
    const int shalf = tid & 1;

    floatx16 acc[2][2];
#pragma unroll
    for (int ti = 0; ti < 2; ++ti)
#pragma unroll
        for (int tj = 0; tj < 2; ++tj)
#pragma unroll
            for (int r = 0; r < 16; ++r) acc[ti][tj][r] = 0.f;

    int bc = 0;
    for (int s = 0; s < NSLICE; ++s) {
        if (s + 2 < NSLICE) {
            int bs = bc + 2; if (bs >= 3) bs -= 3;
            stage(bs, (s + 2) * SLICE);
        }
        // counted wait (T4): retire ONLY stage s; keep s+1/s+2 in flight
        if (s < NSLICE - 2)       asm volatile("s_waitcnt vmcnt(8)" ::: "memory");
        else if (s == NSLICE - 2) asm volatile("s_waitcnt vmcnt(4)" ::: "memory");
        else                      asm volatile("s_waitcnt vmcnt(0)" ::: "memory");
        __builtin_amdgcn_s_barrier();
        asm volatile("" ::: "memory");

        const char* Ab = smem + (bc << 14);
        const char* Bb = Ab + 8192;
        intx8 bf[2];
#pragma unroll
        for (int tj = 0; tj < 2; ++tj) {
            const char* bp = Bb + (wn * 64 + tj * 32 + m32) * SLICE;
            intx4 lo = *(const intx4*)(bp + p0);
            intx4 hi4 = *(const intx4*)(bp + p1);
            bf[tj] = __builtin_shufflevector(lo, hi4, 0, 1, 2, 3, 4, 5, 6, 7);
        }
        __builtin_amdgcn_s_setprio(1);
#pragma unroll
        for (int ti = 0; ti < 2; ++ti) {
            const char* ap = Ab + (wm * 64 + ti * 32 + m32) * SLICE;
            intx4 lo = *(const intx4*)(ap + p0);
            intx4 hi4 = *(const intx4*)(ap + p1);
            intx8 af = __builtin_shufflevector(lo, hi4, 0, 1, 2, 3, 4, 5, 6, 7);
            acc[ti][0] = __builtin_amdgcn_mfma_scale_f32_32x32x64_f8f6f4(
                af, bf[0], acc[ti][0], 0, 0, 0, 127, 0, 127);
            acc[ti][1] = __builtin_amdgcn_mfma_scale_f32_32x32x64_f8f6f4(
                af, bf[1], acc[ti][1], 0, 0, 0, 127, 0, 127);
        }
        __builtin_amdgcn_s_setprio(0);
        asm volatile("" ::: "memory");
        __builtin_amdgcn_s_barrier();
        asm volatile("" ::: "memory");
        bc = (bc + 1 == 3) ? 0 : bc + 1;
    }

    // ---- pass 1: classify once (symmetric), write nv row-major; acc := nv ----
    // 32x32 C layout: col = lane&31, row = (reg&3)+8*(reg>>2)+4*hi
    {
        const int jl0 = wn * 64 + m32, jl1 = jl0 + 32;
        const float sj0 = sqc_s[jl0], sj1 = sqc_s[jl1];
        const int lb0 = (int)labcam_b[jl0], lb1 = (int)labcam_b[jl1];
        const int jc0 = jl0 >> 3, j7_0 = jl0 & 7;
        const int jc1 = jl1 >> 3, j7_1 = jl1 & 7;
#pragma unroll
        for (int ti = 0; ti < 2; ++ti) {
#pragma unroll
            for (int r = 0; r < 16; ++r) {
                const int il = wm * 64 + ti * 32 + (r & 3) + 8 * (r >> 2) + 4 * hi;
                const float si = sqr_s[il];
                const int la = (int)labcam_a[il];
                const int rot = 2 * (il & 7);
                _Float16* drow = Dt + il * DT_LD;

                float d2 = fmaxf(si + sj0 - 2.0f * acc[ti][0][r], 1e-12f);
                int x = la ^ lb0;
                float nv = (x & 15) ? d2 : d2 * BOOST_INV;
                nv = (x & 0xFFF0) ? nv : FINF;
                acc[ti][0][r] = nv;
                drow[(((jc0 + rot) & 15) << 3) + j7_0] = (_Float16)nv;

                d2 = fmaxf(si + sj1 - 2.0f * acc[ti][1][r], 1e-12f);
                x = la ^ lb1;
                nv = (x & 15) ? d2 : d2 * BOOST_INV;
                nv = (x & 0xFFF0) ? nv : FINF;
                acc[ti][1][r] = nv;
                drow[(((jc1 + rot) & 15) << 3) + j7_1] = (_Float16)nv;
            }
        }
    }
    __syncthreads();

    float neg5[5];
    scan_half_row_neg(Dt, srow, shalf, neg5);
    emit_neg(neg5, shalf, negp, r0 + srow, b);

    if (a != b) {
        __syncthreads();             // pass-1 scan reads done before Dt overwrite
        // ---- pass 2: re-layout nv transposed from acc (no recompute) ----
#pragma unroll
        for (int tj = 0; tj < 2; ++tj) {
#pragma unroll
            for (int ti = 0; ti < 2; ++ti) {
                const int jl = wn * 64 + tj * 32 + m32;   // Dt row
                const int cw2 = 2 * (jl & 7);
#pragma unroll
                for (int rq = 0; rq < 4; ++rq) {
                    const int base_row = wm * 64 + ti * 32 + 8 * rq + 4 * hi;
                    halfx4 h;
#pragma unroll
                    for (int e = 0; e < 4; ++e) h[e] = (_Float16)acc[ti][tj][rq * 4 + e];
                    const int pch = (((base_row >> 3) + cw2) & 15);
                    *(halfx4*)(Dt + jl * DT_LD + (pch << 3) + 4 * hi) = h;
                }
            }
        }
        __syncthreads();
        scan_half_row_neg(Dt, srow, shalf, neg5);
        emit_neg(neg5, shalf, negp, c0 + srow, a);
    }
}

// ---- kernel 3: merge 64 fp16 neg-lists/row + final pos list ----
__global__ __launch_bounds__(256) void k_merge_sym(const _Float16* __restrict__ negp,
        const _Float16* __restrict__ posf, const int* __restrict__ epoch_p,
        float* __restrict__ out, float* __restrict__ wsum_p, float* __restrict__ wpsum_p) {
    const int t = threadIdx.x;
    const int rl = t & 31;
    const int sg = t >> 5;
    const int row = blockIdx.x * 32 + rl;
    const float NINF = -__builtin_inff(), PINF = __builtin_inff();
    float n5[5] = {PINF, PINF, PINF, PINF, PINF};
    const size_t rbase = (size_t)row * SLOT_P;
#pragma unroll
    for (int s = 0; s < 8; ++s) {
        const size_t off = (size_t)(sg * 8 + s) * ((size_t)NROW * SLOT_P) + rbase;
        halfx8 nv = *(const halfx8*)(negp + off);
#pragma unroll
        for (int e = 0; e < 8; ++e) { float f = (float)nv[e]; if (f < n5[4]) ins_asc(n5, f); }
    }
    __shared__ __align__(16) _Float16 ln[32][8][8];
    const int sw = (sg + rl) & 7;
    {
        halfx8 hn;
#pragma unroll
        for (int k = 0; k < 5; ++k) hn[k] = (_Float16)n5[k];
        hn[5] = hn[6] = hn[7] = (_Float16)PINF;
        *(halfx8*)&ln[rl][sw][0] = hn;
    }
    __syncthreads();
    if (t < 32) {
        float N5[5] = {PINF, PINF, PINF, PINF, PINF};
#pragma unroll
        for (int g = 0; g < 8; ++g) {
            halfx8 nv = *(const halfx8*)&ln[t][g][0];
#pragma unroll
            for (int e = 0; e < 8; ++e) { float f = (float)nv[e]; if (f < N5[4]) ins_asc(N5, f); }
        }
        const int orow = blockIdx.x * 32 + t;
        halfx8 pv = *(const halfx8*)(posf + (size_t)orow * SLOT_P);
        float s = 0.f; int c = 0;
#pragma unroll
        for (int k = 0; k < 5; ++k) { float f = (float)pv[k]; bool fin = (f > NINF); s += fin ? sqrtf(f) : 0.f; c += fin ? 1 : 0; }
        float d_ap = (c > 0) ? s / (float)c : NINF;
        s = 0.f; c = 0;
#pragma unroll
        for (int k = 0; k < 5; ++k) { bool fin = (N5[k] < PINF); s += fin ? sqrtf(N5[k]) : 0.f; c += fin ? 1 : 0; }
        float d_an = (c > 0) ? s / (float)c : PINF;

        out[1 + orow] = d_ap;
        out[1 + NROW + orow] = d_an;
        float diff = d_ap - d_an;
        float w0 = 1.0f / (1.0f + expf(-2.0f * diff));       // sigmoid(ALPHA*diff)
        float p;
        if (*epoch_p < 10) {
            p = fmaxf(diff, 0.0f) + log1pf(expf(-fabsf(diff)));  // stable softplus
        } else {
            p = fmaxf(diff + 0.3f, 0.0f);                    // relu(diff + MARGIN)
        }
        float wp = w0 * p;
#pragma unroll
        for (int o = 16; o > 0; o >>= 1) { w0 += __shfl_down(w0, o, 32); wp += __shfl_down(wp, o, 32); }
        if (t == 0) { wsum_p[blockIdx.x] = w0; wpsum_p[blockIdx.x] = wp; }
    }
}

// ---- kernel 4: finalize loss scalar (256 partials, one wave) ----
__global__ void k_finalize(const float* __restrict__ wsum_p, const float* __restrict__ wpsum_p,
                           float* __restrict__ out) {
    const int t = threadIdx.x;   // 64 threads
    float sw  = wsum_p[t] + wsum_p[t + 64] + wsum_p[t + 128] + wsum_p[t + 192];
    float swp = wpsum_p[t] + wpsum_p[t + 64] + wpsum_p[t + 128] + wpsum_p[t + 192];
#pragma unroll
    for (int o = 32; o > 0; o >>= 1) { sw += __shfl_down(sw, o); swp += __shfl_down(swp, o); }
    if (t == 0) {
        float M = fmaxf(sw / (float)NROW, 1e-12f);
        out[0] = swp / ((float)NROW * M);
    }
}

extern "C" void kernel_launch(void* const* d_in, const int* in_sizes, int n_in,
                              void* d_out, int out_size, void* d_ws, size_t ws_size,
                              hipStream_t stream) {
    const float* feats  = (const float*)d_in[0];
    const int*   labels = (const int*)d_in[1];
    const int*   camids = (const int*)d_in[2];
    const int*   epoch  = (const int*)d_in[3];
    float* out = (float*)d_out;
    char* ws = (char*)d_ws;

    // workspace layout (~24.4 MB; ws proven >= 44 MB in R4-R11)
    unsigned char* xb = (unsigned char*)ws;                            // 16,777,216 B
    float* sq = (float*)(ws + 16777216);                               //     32,768 B
    const size_t NEG_HALVES = (size_t)KL_SYM * NROW * SLOT_P;          // 8 MB
    _Float16* negp = (_Float16*)(ws + 16777216 + 32768);
    _Float16* posf = negp + NEG_HALVES;                                // 128 KB
    float* wsum_p  = (float*)((char*)(posf + (size_t)NROW * SLOT_P));
    float* wpsum_p = wsum_p + MERGE_BLOCKS;

    k_normalize<<<NROW / 4, 256, 0, stream>>>(feats, xb, sq);
    k_main<<<NPOSB + NTILE, 256, 0, stream>>>(xb, sq, labels, camids, negp, posf);
    k_merge_sym<<<MERGE_BLOCKS, 256, 0, stream>>>(negp, posf, epoch, out, wsum_p, wpsum_p);
    k_finalize<<<1, 64, 0, stream>>>(wsum_p, wpsum_p, out);
}